// Round 9
// baseline (489.155 us; speedup 1.0000x reference)
//
#include <hip/hip_runtime.h>

typedef unsigned short u16;
typedef unsigned int   u32;

typedef __bf16 bf16x8 __attribute__((ext_vector_type(8)));
typedef float  f32x4  __attribute__((ext_vector_type(4)));

__device__ __forceinline__ float bf2f(u16 u) {
  union { u32 i; float f; } v; v.i = ((u32)u) << 16; return v.f;
}
__device__ __forceinline__ u16 f2bf(float f) {
  union { float f; u32 i; } v; v.f = f;
  u32 r = v.i + 0x7fffu + ((v.i >> 16) & 1u);   // RNE
  return (u16)(r >> 16);
}
__device__ __forceinline__ u32 cvtpk(float a, float b) {
  u32 r;
  asm("v_cvt_pk_bf16_f32 %0, %1, %2" : "=v"(r) : "v"(a), "v"(b));
  return r;
}

__device__ __forceinline__ f32x4 mfma16(bf16x8 a, bf16x8 b, f32x4 c) {
  return __builtin_amdgcn_mfma_f32_16x16x32_bf16(a, b, c, 0, 0, 0);
}

#define GLOAD_LDS16(gsrc, ldst) \
  __builtin_amdgcn_global_load_lds((const __attribute__((address_space(1))) void*)(gsrc), \
                                   (__attribute__((address_space(3))) void*)(ldst), 16, 0, 0)

// 0.125 * log2(e): folded into Q so softmax can use exp2
#define QSCALE 0.18033688011112042f

// B-panel row permutation (128-row panels): fragment n / lane qi covers 4
// CONSECUTIVE columns qi*4+n -> packed stores.
__device__ __forceinline__ int bperm(int slot) {
  return (slot & 64) + ((slot & 15) << 2) + ((slot >> 4) & 3);
}
// 64-row variant: fragment n (0..1) / lane qi covers 2 consecutive cols qi*2+n.
__device__ __forceinline__ int bperm64(int slot) {
  return (slot & 32) + ((slot & 15) << 1) + ((slot >> 4) & 1);
}

// ---------------- weight convert: transposed (default) or plain bf16 copy ----------------
struct W16 { const float* p[16]; };

__global__ __launch_bounds__(256)
void wconv(W16 srcs, u32 plainmask, u16* __restrict__ base)
{
  __shared__ float tile[64][65];
  const int tx = threadIdx.x;           // 0..63
  const int ty = threadIdx.y;           // 0..3
  const int n0 = blockIdx.x * 64;
  const int k0 = blockIdx.y * 64;
  // constant-index select (avoid runtime-indexed kernarg aggregate -> scratch)
  const float* W = srcs.p[0];
#pragma unroll
  for (int k = 1; k < 16; ++k) if ((int)blockIdx.z == k) W = srcs.p[k];
  u16* Wt = base + ((size_t)blockIdx.z << 20);
  if ((plainmask >> blockIdx.z) & 1u) {
#pragma unroll
    for (int j = 0; j < 16; ++j) {
      int k = k0 + ty + j * 4;
      Wt[(size_t)k * 1024 + n0 + tx] = f2bf(W[(size_t)k * 1024 + n0 + tx]);
    }
    return;
  }
#pragma unroll
  for (int j = 0; j < 16; ++j) {
    int k = ty + j * 4;
    tile[k][tx] = W[(size_t)(k0 + k) * 1024 + n0 + tx];
  }
  __syncthreads();
  const int kp = tx & 31;               // k-pair index
  const int nx = (tx >> 5) * 4;         // extra n offset
#pragma unroll
  for (int j = 0; j < 8; ++j) {
    int n = ty + nx + j * 8;
    u32 w = (u32)f2bf(tile[2 * kp][n]) | ((u32)f2bf(tile[2 * kp + 1][n]) << 16);
    ((u32*)(Wt + (size_t)(n0 + n) * 1024 + k0))[kp] = w;
  }
}

// ---------------- bias combine GEMV: out[n] = v . W[:,n] + s1*a1[n] + a2[n] ----------------
struct BiasJob { const float* v; const float* W; const float* a1; const float* a2;
                 float s1; float* out; };

__global__ __launch_bounds__(256)
void bias_comb(BiasJob j0, BiasJob j1, BiasJob j2, BiasJob j3)
{
  BiasJob J = (blockIdx.y == 0) ? j0 : (blockIdx.y == 1) ? j1 : (blockIdx.y == 2) ? j2 : j3;
  const int t = threadIdx.x;
  const int cl = t & 63;
  const int seg = t >> 6;                       // 4 K-segments of 256
  const int n = blockIdx.x * 64 + cl;           // grid.x = 16
  float acc = 0.f;
  const int jb = seg * 256;
#pragma unroll 8
  for (int j = 0; j < 256; ++j) acc += J.v[jb + j] * J.W[(size_t)(jb + j) * 1024 + n];
  __shared__ float red[4][64];
  red[seg][cl] = acc;
  __syncthreads();
  if (seg == 0) {
    float r = red[0][cl] + red[1][cl] + red[2][cl] + red[3][cl]
            + J.s1 * J.a1[n] + (J.a2 ? J.a2[n] : 0.f);
    J.out[n] = r;
  }
}

// ---------------- LayerNorm (row = 1024) -> bf16, dual source ----------------
__global__ __launch_bounds__(256)
void ln_bf16(const float* __restrict__ in0, const float* __restrict__ g0,
             const float* __restrict__ b0, u16* __restrict__ out0,
             const float* __restrict__ in1, const float* __restrict__ g1,
             const float* __restrict__ b1, u16* __restrict__ out1, int split)
{
  int row = blockIdx.x;
  const float *in, *gw, *bw; u16* out;
  if (row < split) { in = in0; gw = g0; bw = b0; out = out0; }
  else             { in = in1; gw = g1; bw = b1; out = out1; row -= split; }
  const int t = threadIdx.x;
  const float4 v = ((const float4*)(in + (size_t)row * 1024))[t];
  float s  = v.x + v.y + v.z + v.w;
  float sq = v.x*v.x + v.y*v.y + v.z*v.z + v.w*v.w;
#pragma unroll
  for (int o = 32; o >= 1; o >>= 1) {
    s  += __shfl_xor(s, o);
    sq += __shfl_xor(sq, o);
  }
  __shared__ float red[8];
  const int wv = t >> 6;
  if ((t & 63) == 0) { red[wv] = s; red[4 + wv] = sq; }
  __syncthreads();
  s  = red[0] + red[1] + red[2] + red[3];
  sq = red[4] + red[5] + red[6] + red[7];
  const float mean = s * (1.f / 1024.f);
  const float var  = sq * (1.f / 1024.f) - mean * mean;
  const float rstd = rsqrtf(var + 1e-6f);
  const float4 g4 = ((const float4*)gw)[t];
  const float4 b4 = ((const float4*)bw)[t];
  uint2 w;
  w.x = cvtpk((v.x - mean) * rstd * g4.x + b4.x, (v.y - mean) * rstd * g4.y + b4.y);
  w.y = cvtpk((v.z - mean) * rstd * g4.z + b4.z, (v.w - mean) * rstd * g4.w + b4.w);
  ((uint2*)(out + (size_t)row * 1024))[t] = w;
}

// ---------------- segmented GEMM: C = A[M,K](bf16) @ Bt[N,K](bf16)^T ----------------
// modes: 0 bf16 row-major; 1 bf16 [B,H,L,HD]; 3 f32 (+f32 res); 4 bf16 (+bf16 res);
// 5 V-transposed (A=weight rows, Bt=activation rows), bias indexed by ROW.
struct GOut { void* ptr; const float* bias; const void* res; float oscale; int mode; };
struct Seg  { const u16* A; const u16* Bt; GOut od[2]; int odshift; int gx; int start; };
struct Segs { Seg s[8]; int total; };

template<int BM, int TPB>
__global__ __launch_bounds__(TPB)
void gemm_multi(Segs S, int K)
{
  constexpr int NW   = TPB / 64;        // waves per block
  constexpr int ROWG = NW / 2;          // row wave-groups (2 col groups)
  constexpr int WM   = BM / ROWG;       // rows per wave
  constexpr int MF   = WM / 16;         // m-fragments per wave
  constexpr int nA   = BM / 8;          // A chunks
  constexpr int PW   = (nA + 16) / NW;  // chunks per wave
  __shared__ u16 As[BM * 64];
  __shared__ u16 Bs[128 * 64];
  const int t    = threadIdx.x;
  const int lane = t & 63;
  const int wave = t >> 6;
  const int qi   = lane & 15;
  const int g    = lane >> 4;
  const int cpx  = S.total >> 3;        // XCD swizzle (total % 8 == 0)
  const int flat = blockIdx.x;
  const int nid  = (flat & 7) * cpx + (flat >> 3);
  // constant-index segment select (rule #20: no runtime-indexed aggregate)
  Seg sg = S.s[0];
#pragma unroll
  for (int k = 1; k < 8; ++k) { Seg c = S.s[k]; if (nid >= c.start) sg = c; }
  const int local = nid - sg.start;
  const int bx = local % sg.gx;
  const int by = local / sg.gx;
  const int row0 = by * BM;
  const int col0 = bx * 128;
  const int wrow = (wave >> 1) * WM;
  const int wcol = (wave & 1) * 64;

  f32x4 acc[MF][4] = {};

  const int srow  = lane >> 3;
  const int skseg = (lane & 7) * 8;
  const u16* A  = sg.A;
  const u16* Bt = sg.Bt;

  for (int kt = 0; kt < K; kt += 64) {
    __syncthreads();
#pragma unroll
    for (int i = 0; i < PW; ++i) {
      int chunk = wave * PW + i;
      if (chunk < nA) {
        GLOAD_LDS16(A + (size_t)(row0 + chunk * 8 + srow) * K + kt + skseg, As + chunk * 512);
      } else {
        int cb = chunk - nA;
        int grow = bperm(cb * 8 + srow);
        GLOAD_LDS16(Bt + (size_t)(col0 + grow) * K + kt + skseg, Bs + cb * 512);
      }
    }
    __syncthreads();
#pragma unroll
    for (int kk = 0; kk < 2; ++kk) {
      bf16x8 af[MF], bfv[4];
#pragma unroll
      for (int m = 0; m < MF; ++m)
        af[m] = *(const bf16x8*)(As + (wrow + m * 16 + qi) * 64 + kk * 32 + g * 8);
#pragma unroll
      for (int n = 0; n < 4; ++n)
        bfv[n] = *(const bf16x8*)(Bs + (wcol + n * 16 + qi) * 64 + kk * 32 + g * 8);
#pragma unroll
      for (int m = 0; m < MF; ++m)
#pragma unroll
        for (int n = 0; n < 4; ++n)
          acc[m][n] = mfma16(af[m], bfv[n], acc[m][n]);
    }
  }

  // constant-index output-descriptor select
  GOut od = sg.od[0];
  if ((bx >> sg.odshift) != 0) od = sg.od[1];
  const int cbase = (bx & ((1 << sg.odshift) - 1)) * 128 + wcol;
  const int c0 = cbase + (qi << 2);     // 4 consecutive output cols per lane
  float4 b4; b4.x = b4.y = b4.z = b4.w = 0.f;
  if (od.mode != 5 && od.bias) b4 = *(const float4*)(od.bias + c0);
#pragma unroll
  for (int m = 0; m < MF; ++m) {
#pragma unroll
    for (int j = 0; j < 4; ++j) {
      const int row = row0 + wrow + m * 16 + g * 4 + j;
      float v0 = (acc[m][0][j] + b4.x) * od.oscale;
      float v1 = (acc[m][1][j] + b4.y) * od.oscale;
      float v2 = (acc[m][2][j] + b4.z) * od.oscale;
      float v3 = (acc[m][3][j] + b4.w) * od.oscale;
      if (od.mode == 0) {
        uint2 w; w.x = cvtpk(v0, v1); w.y = cvtpk(v2, v3);
        *(uint2*)((u16*)od.ptr + (size_t)row * 1024 + c0) = w;
      } else if (od.mode == 1) {
        int bb = row >> 9, l = row & 511, hh = c0 >> 6, hd = c0 & 63;
        uint2 w; w.x = cvtpk(v0, v1); w.y = cvtpk(v2, v3);
        *(uint2*)((u16*)od.ptr + (((size_t)(bb * 16 + hh) * 512) + l) * 64 + hd) = w;
      } else if (od.mode == 5) {
        float br = od.bias[row];
        int hh = row >> 6, hd = row & 63, bb = c0 >> 9, l0 = c0 & 511;
        uint2 w; w.x = cvtpk(v0 + br, v1 + br); w.y = cvtpk(v2 + br, v3 + br);
        *(uint2*)((u16*)od.ptr + (((size_t)(bb * 16 + hh) * 64) + hd) * 512 + l0) = w;
      } else if (od.mode == 3) {
        float4 o; o.x = v0; o.y = v1; o.z = v2; o.w = v3;
        if (od.res) {
          const float4 r4 = *(const float4*)((const float*)od.res + (size_t)row * 1024 + c0);
          o.x += r4.x; o.y += r4.y; o.z += r4.z; o.w += r4.w;
        }
        *(float4*)((float*)od.ptr + (size_t)row * 1024 + c0) = o;
      } else { // 4: bf16 + bf16 res
        uint2 r = *(const uint2*)((const u16*)od.res + (size_t)row * 1024 + c0);
        uint2 w;
        w.x = cvtpk(v0 + bf2f((u16)(r.x & 0xffffu)), v1 + bf2f((u16)(r.x >> 16)));
        w.y = cvtpk(v2 + bf2f((u16)(r.y & 0xffffu)), v3 + bf2f((u16)(r.y >> 16)));
        *(uint2*)((u16*)od.ptr + (size_t)row * 1024 + c0) = w;
      }
    }
  }
}

// ---------------- quad gate GEMM (4 GEMMs + gate), BM=64/BN=64, 1024 blocks ------
// gated = (sctx@WcS+bcs)*(xctx@Wx+bx) + (xctx@WcX+bcx)*(sctx@Ws+bs)
__global__ __launch_bounds__(256)
void gemm_quad_gate(const u16* __restrict__ A1, const u16* __restrict__ A2,
                    const u16* __restrict__ BWs, const u16* __restrict__ BWx,
                    const u16* __restrict__ BWcs, const u16* __restrict__ BWcx,
                    const float* __restrict__ bs, const float* __restrict__ bx,
                    const float* __restrict__ bcs, const float* __restrict__ bcx,
                    u16* __restrict__ out)
{
  __shared__ u16 As1[64 * 64];
  __shared__ u16 As2[64 * 64];
  __shared__ u16 Bs0[64 * 64];
  __shared__ u16 Bs1[64 * 64];
  __shared__ u16 Bs2[64 * 64];
  __shared__ u16 Bs3[64 * 64];
  const int t    = threadIdx.x;
  const int lane = t & 63;
  const int wave = t >> 6;
  const int qi   = lane & 15;
  const int g    = lane >> 4;
  const int flat = blockIdx.x;                  // 1024 blocks
  const int nid  = (flat & 7) * 128 + (flat >> 3);
  const int bxi  = nid & 15;                    // 16 col-blocks of 64
  const int byi  = nid >> 4;                    // 64 row-blocks of 64
  const int row0 = byi * 64;
  const int col0 = bxi * 64;
  const int wrow = (wave >> 1) * 32;
  const int wcol = (wave & 1) * 32;

  f32x4 aS1[2][2] = {}, aX1[2][2] = {}, aS2[2][2] = {}, aX2[2][2] = {};

  const int srow  = lane >> 3;
  const int skseg = (lane & 7) * 8;

  for (int kt = 0; kt < 1024; kt += 64) {
    __syncthreads();
#pragma unroll
    for (int i = 0; i < 12; ++i) {
      int chunk = wave * 12 + i;                // 0..47
      if (chunk < 8) {
        GLOAD_LDS16(A1 + (size_t)(row0 + chunk * 8 + srow) * 1024 + kt + skseg, As1 + chunk * 512);
      } else if (chunk < 16) {
        int cb = chunk - 8;
        GLOAD_LDS16(A2 + (size_t)(row0 + cb * 8 + srow) * 1024 + kt + skseg, As2 + cb * 512);
      } else {
        int w2 = chunk - 16;
        int cb = w2 & 7;
        int grow = bperm64(cb * 8 + srow);
        const size_t goff = (size_t)(col0 + grow) * 1024 + kt + skseg;
        if (w2 < 8)       { GLOAD_LDS16(BWs  + goff, Bs0 + cb * 512); }
        else if (w2 < 16) { GLOAD_LDS16(BWx  + goff, Bs1 + cb * 512); }
        else if (w2 < 24) { GLOAD_LDS16(BWcs + goff, Bs2 + cb * 512); }
        else              { GLOAD_LDS16(BWcx + goff, Bs3 + cb * 512); }
      }
    }
    __syncthreads();
#pragma unroll
    for (int kk = 0; kk < 2; ++kk) {
      bf16x8 a1[2], a2[2], b0[2], b1[2], b2[2], b3[2];
#pragma unroll
      for (int m = 0; m < 2; ++m) {
        a1[m] = *(const bf16x8*)(As1 + (wrow + m * 16 + qi) * 64 + kk * 32 + g * 8);
        a2[m] = *(const bf16x8*)(As2 + (wrow + m * 16 + qi) * 64 + kk * 32 + g * 8);
      }
#pragma unroll
      for (int n = 0; n < 2; ++n) {
        const int ro = (wcol + n * 16 + qi) * 64 + kk * 32 + g * 8;
        b0[n] = *(const bf16x8*)(Bs0 + ro);
        b1[n] = *(const bf16x8*)(Bs1 + ro);
        b2[n] = *(const bf16x8*)(Bs2 + ro);
        b3[n] = *(const bf16x8*)(Bs3 + ro);
      }
#pragma unroll
      for (int m = 0; m < 2; ++m)
#pragma unroll
        for (int n = 0; n < 2; ++n) {
          aS1[m][n] = mfma16(a1[m], b0[n], aS1[m][n]);
          aX1[m][n] = mfma16(a2[m], b1[n], aX1[m][n]);
          aS2[m][n] = mfma16(a1[m], b2[n], aS2[m][n]);
          aX2[m][n] = mfma16(a2[m], b3[n], aX2[m][n]);
        }
    }
  }

  const int c0 = col0 + wcol + (qi << 1);       // 2 consecutive cols per lane
  const float2 vbs  = *(const float2*)(bs  + c0);
  const float2 vbx  = *(const float2*)(bx  + c0);
  const float2 vbcs = *(const float2*)(bcs + c0);
  const float2 vbcx = *(const float2*)(bcx + c0);
#pragma unroll
  for (int m = 0; m < 2; ++m) {
#pragma unroll
    for (int j = 0; j < 4; ++j) {
      const int row = row0 + wrow + m * 16 + g * 4 + j;
      float sv0 = aS1[m][0][j] + vbs.x,  sv1 = aS1[m][1][j] + vbs.y;
      float xv0 = aX1[m][0][j] + vbx.x,  xv1 = aX1[m][1][j] + vbx.y;
      float sg0 = aS2[m][0][j] + vbcs.x, sg1 = aS2[m][1][j] + vbcs.y;
      float xg0 = aX2[m][0][j] + vbcx.x, xg1 = aX2[m][1][j] + vbcx.y;
      u32 w = cvtpk(sg0 * xv0 + xg0 * sv0, sg1 * xv1 + xg1 * sv1);
      *(u32*)(out + (size_t)row * 1024 + c0) = w;
    }
  }
}

// ---------------- bilinear K=2048 (virtual concat), BM=64/BN=64, 1024 blocks ------
__global__ __launch_bounds__(256)
void gemm_bilinear(const u16* __restrict__ A1, const u16* __restrict__ A2,
                   const u16* __restrict__ B1a, const u16* __restrict__ B1b,
                   const u16* __restrict__ B2a, const u16* __restrict__ B2b,
                   const float* __restrict__ bias1, const float* __restrict__ bias2,
                   const int* __restrict__ fm, u16* __restrict__ out)
{
  __shared__ u16 As[64 * 64];
  __shared__ u16 B1s[64 * 64];
  __shared__ u16 B2s[64 * 64];
  const int t    = threadIdx.x;
  const int lane = t & 63;
  const int wave = t >> 6;
  const int qi   = lane & 15;
  const int g    = lane >> 4;
  const int flat = blockIdx.x;                  // 1024 blocks
  const int nid  = (flat & 7) * 128 + (flat >> 3);
  const int bxi  = nid & 15;                    // 16 col-blocks of 64
  const int byi  = nid >> 4;                    // 64 row-blocks of 64
  const int row0 = byi * 64;
  const int col0 = bxi * 64;
  const int wrow = (wave >> 1) * 32;
  const int wcol = (wave & 1) * 32;

  f32x4 accS[2][2] = {};
  f32x4 accV[2][2] = {};

  const int srow  = lane >> 3;
  const int skseg = (lane & 7) * 8;

  for (int kt = 0; kt < 2048; kt += 64) {
    const u16* Ap  = (kt < 1024) ? A1  : A2;
    const u16* B1p = (kt < 1024) ? B1a : B1b;
    const u16* B2p = (kt < 1024) ? B2a : B2b;
    const int kto = kt & 1023;
    __syncthreads();
#pragma unroll
    for (int i = 0; i < 6; ++i) {
      int chunk = wave * 6 + i;                 // 0..23
      if (chunk < 8) {
        GLOAD_LDS16(Ap + (size_t)(row0 + chunk * 8 + srow) * 1024 + kto + skseg, As + chunk * 512);
      } else if (chunk < 16) {
        int cb = chunk - 8;
        int grow = bperm64(cb * 8 + srow);
        GLOAD_LDS16(B1p + (size_t)(col0 + grow) * 1024 + kto + skseg, B1s + cb * 512);
      } else {
        int cb = chunk - 16;
        int grow = bperm64(cb * 8 + srow);
        GLOAD_LDS16(B2p + (size_t)(col0 + grow) * 1024 + kto + skseg, B2s + cb * 512);
      }
    }
    __syncthreads();
#pragma unroll
    for (int kk = 0; kk < 2; ++kk) {
      bf16x8 af[2], b1[2], b2[2];
#pragma unroll
      for (int m = 0; m < 2; ++m)
        af[m] = *(const bf16x8*)(As + (wrow + m * 16 + qi) * 64 + kk * 32 + g * 8);
#pragma unroll
      for (int n = 0; n < 2; ++n) {
        const int ro = (wcol + n * 16 + qi) * 64 + kk * 32 + g * 8;
        b1[n] = *(const bf16x8*)(B1s + ro);
        b2[n] = *(const bf16x8*)(B2s + ro);
      }
#pragma unroll
      for (int m = 0; m < 2; ++m)
#pragma unroll
        for (int n = 0; n < 2; ++n) {
          accS[m][n] = mfma16(af[m], b1[n], accS[m][n]);
          accV[m][n] = mfma16(af[m], b2[n], accV[m][n]);
        }
    }
  }

  const int c0 = col0 + wcol + (qi << 1);
  const float2 b1v = *(const float2*)(bias1 + c0);
  const float2 b2v = *(const float2*)(bias2 + c0);
#pragma unroll
  for (int m = 0; m < 2; ++m) {
#pragma unroll
    for (int j = 0; j < 4; ++j) {
      const int row = row0 + wrow + m * 16 + g * 4 + j;
      const float neg = fm[row] ? 0.f : -1e30f;
      float s0 = accS[m][0][j] + b1v.x + neg;
      float s1 = accS[m][1][j] + b1v.y + neg;
      float o0 = (1.f / (1.f + expf(-s0))) * (accV[m][0][j] + b2v.x);
      float o1 = (1.f / (1.f + expf(-s1))) * (accV[m][1][j] + b2v.y);
      *(u32*)(out + (size_t)row * 1024 + c0) = cvtpk(o0, o1);
    }
  }
}

// ---------------- fused flash attention: fixed-shift softmax, 2 q-chains/wave ----
__global__ __launch_bounds__(256)
void attn_fused(const u16* __restrict__ Q,
                const u16* __restrict__ K0, const u16* __restrict__ V0,
                const u16* __restrict__ K1, const u16* __restrict__ V1,
                const int* __restrict__ qmask,
                const int* __restrict__ km0, const int* __restrict__ km1,
                u16* __restrict__ ctx0, u16* __restrict__ ctx1)
{
  const int T = 512, L = 512;
  const int lane = threadIdx.x & 63;
  const int wave = threadIdx.x >> 6;
  const int qi = lane & 15;
  const int g  = lane >> 4;
  const int bid = blockIdx.x;               // 0..1023
  const int z   = bid >> 9;
  const int ib  = bid & 511;
  const int xcd = ib & 7;
  const int iw  = ib >> 3;                  // 0..63
  const int bh  = xcd * 16 + (iw & 15);
  const int qblk = iw >> 4;                 // 0..3
  const int b  = bh >> 4;
  const int h  = bh & 15;
  const int q0a = qblk * 128 + wave * 16;
  const int q0b = q0a + 64;

  const u16* Kh = z ? K1 : K0;
  const u16* Vt = z ? V1 : V0;
  const int* kmb = (z ? km1 : km0) + b * T;
  u16* ctx = z ? ctx1 : ctx0;

  __shared__ u16 Plds[4][2][16 * 136];      // per-wave, per-chain P^T bounce
  u16* Pa = Plds[wave][0];
  u16* Pb = Plds[wave][1];

  const size_t qoffa = ((size_t)bh * L + q0a + qi) * 64;
  const size_t qoffb = ((size_t)bh * L + q0b + qi) * 64;
  const bf16x8 qa0 = *(const bf16x8*)(Q + qoffa + g * 8);
  const bf16x8 qa1 = *(const bf16x8*)(Q + qoffa + 32 + g * 8);
  const bf16x8 qb0 = *(const bf16x8*)(Q + qoffb + g * 8);
  const bf16x8 qb1 = *(const bf16x8*)(Q + qoffb + 32 + g * 8);

  const float qma = (float)qmask[b * L + q0a + qi];
  const float qmb = (float)qmask[b * L + q0b + qi];
  float tsa = 0.f, tsb = 0.f;
  f32x4 ofa[4] = {}, ofb[4] = {};

  for (int kb = 0; kb < T; kb += 128) {     // 4 iterations
    f32x4 sta[8], stb[8];
    __builtin_amdgcn_s_setprio(1);
#pragma unroll
    for (int s = 0; s < 8; ++s) {
      const size_t koff = ((size_t)bh * T + kb + s * 16 + qi) * 64;
      bf16x8 k0v = *(const bf16x8*)(Kh + koff + g * 8);
      bf16x8 k1v = *(const bf16x8*)(Kh + koff + 32 + g * 8);
      f32x4 za = {}; za = mfma16(k0v, qa0, za); sta[s] = mfma16(k1v, qa1, za);
      f32x4 zb = {}; zb = mfma16(k0v, qb0, zb); stb[s] = mfma16(k1v, qb1, zb);
    }
    __builtin_amdgcn_s_setprio(0);
#pragma unroll
    for (int s = 0; s < 8; ++s) {
      int4 km4 = *(const int4*)(kmb + kb + s * 16 + g * 4);
      const float m0 = km4.x ? 0.f : -1e30f;
      const float m1 = km4.y ? 0.f : -1e30f;
      const float m2 = km4.z ? 0.f : -1e30f;
      const float m3 = km4.w ? 0.f : -1e30f;
      float a0 = exp2f(fmaf(sta[s][0] + m0, qma, -20.f));
      float a1 = exp2f(fmaf(sta[s][1] + m1, qma, -20.f));
      float a2 = exp2f(fmaf(sta[s][2] + m2, qma, -20.f));
      float a3 = exp2f(fmaf(sta[s][3] + m3, qma, -20.f));
      tsa += (a0 + a1) + (a2 + a3);
      uint2 wa; wa.x = cvtpk(a0, a1); wa.y = cvtpk(a2, a3);
      *(uint2*)(Pa + qi * 136 + s * 16 + g * 4) = wa;
      float p0 = exp2f(fmaf(stb[s][0] + m0, qmb, -20.f));
      float p1 = exp2f(fmaf(stb[s][1] + m1, qmb, -20.f));
      float p2 = exp2f(fmaf(stb[s][2] + m2, qmb, -20.f));
      float p3 = exp2f(fmaf(stb[s][3] + m3, qmb, -20.f));
      tsb += (p0 + p1) + (p2 + p3);
      uint2 wb; wb.x = cvtpk(p0, p1); wb.y = cvtpk(p2, p3);
      *(uint2*)(Pb + qi * 136 + s * 16 + g * 4) = wb;
    }
    bf16x8 paf[4], pbf[4];
#pragma unroll
    for (int ks = 0; ks < 4; ++ks) {
      paf[ks] = *(const bf16x8*)(Pa + qi * 136 + ks * 32 + g * 8);
      pbf[ks] = *(const bf16x8*)(Pb + qi * 136 + ks * 32 + g * 8);
    }
    __builtin_amdgcn_s_setprio(1);
#pragma unroll
    for (int nf = 0; nf < 4; ++nf) {
      f32x4 oa = ofa[nf], ob = ofb[nf];
#pragma unroll
      for (int ks = 0; ks < 4; ++ks) {
        const size_t voff = ((size_t)bh * 64 + nf * 16 + qi) * (size_t)T + kb + ks * 32 + g * 8;
        bf16x8 vb = *(const bf16x8*)(Vt + voff);
        oa = mfma16(paf[ks], vb, oa);
        ob = mfma16(pbf[ks], vb, ob);
      }
      ofa[nf] = oa; ofb[nf] = ob;
    }
    __builtin_amdgcn_s_setprio(0);
  }
  tsa += __shfl_xor(tsa, 16); tsa += __shfl_xor(tsa, 32);
  tsb += __shfl_xor(tsb, 16); tsb += __shfl_xor(tsb, 32);
  const float lia = 1.f / tsa;
  const float lib = 1.f / tsb;
  float lja[4], ljb[4];
#pragma unroll
  for (int j = 0; j < 4; ++j) {
    lja[j] = __shfl(lia, g * 4 + j);
    ljb[j] = __shfl(lib, g * 4 + j);
  }
#pragma unroll
  for (int nf = 0; nf < 4; ++nf) {
    int col = h * 64 + nf * 16 + qi;
#pragma unroll
    for (int j = 0; j < 4; ++j) {
      int rowa = q0a + g * 4 + j;
      int rowb = q0b + g * 4 + j;
      ctx[((size_t)b * L + rowa) * 1024 + col] = f2bf(ofa[nf][j] * lja[j]);
      ctx[((size_t)b * L + rowb) * 1024 + col] = f2bf(ofb[nf][j] * ljb[j]);
    }
  }
}

// ---------------- driver ----------------
extern "C" void kernel_launch(void* const* d_in, const int* in_sizes, int n_in,
                              void* d_out, int out_size, void* d_ws, size_t ws_size,
                              hipStream_t stream)
{
  (void)in_sizes; (void)n_in; (void)out_size; (void)ws_size;
  const float* from = (const float*)d_in[0];
  const float* to_t = (const float*)d_in[1];
  const float* ln1g = (const float*)d_in[2];
  const float* ln1b = (const float*)d_in[3];
  const float* lntg = (const float*)d_in[4];
  const float* lntb = (const float*)d_in[5];
  const float* ln2g = (const float*)d_in[6];
  const float* ln2b = (const float*)d_in[7];
  const int* fmask = (const int*)d_in[38];
  const int* tmask = (const int*)d_in[39];

  char* ws = (char*)d_ws;
  const size_t MB = 1ull << 20;
  auto WT = [&](int i) { return (u16*)(ws + (size_t)i * 2 * MB); };   // slots 0..19 (40MB)
  // WT: 0 Wq^T 1 Wfk^T 2 Wfv^T 3 Wtk^T 4 Wtv^T 5 Ws^T 6 Wx^T 7 Wsg^T 8 Wxg^T
  //     9 Wg(plain) 10 W1^T 11 W2^T 12 Wd1^T 13 Wd2^T 14 Ws(plain) 15 Wx(plain)
  //     16 WcS^T=(Ws@Wsg)^T 17 WcX^T 18 WcG1^T=(Wg@W1)^T 19 WcG2^T
  float* bc_s   = (float*)(ws + 40 * MB);
  float* bc_x   = bc_s + 1024;
  float* bias1v = bc_s + 2048;
  float* bias2v = bc_s + 3072;
  u16*   xbf    = (u16*)(ws + 42 * MB);
  u16*   tbf    = (u16*)(ws + 50 * MB);
  u16*   qh     = (u16*)(ws + 58 * MB);
  u16*   fkh    = (u16*)(ws + 66 * MB);
  u16*   fvt    = (u16*)(ws + 74 * MB);
  u16*   tkh    = (u16*)(ws + 82 * MB);
  u16*   tvt    = (u16*)(ws + 90 * MB);
  u16*   xctx   = (u16*)(ws + 98 * MB);
  // temporally-disjoint reuse:
  u16*   sctx   = (u16*)(ws + 50 * MB);         // over tbf (dead after mega1)
  u16*   gated  = (u16*)(ws + 90 * MB);         // over tvt (dead after attn)
  u16*   abf    = (u16*)(ws + 98 * MB);         // over xctx (dead after quad)
  float* resid  = (float*)(ws + 58 * MB);       // 16MB over qh/fkh (dead after bilinear)
  u16*   lnr    = (u16*)(ws + 74 * MB);         // over fvt (dead)

  W16 wsrc;
  const int widx[14] = {8, 10, 12, 14, 16, 18, 20, 22, 24, 26, 28, 31, 34, 36};
  for (int i = 0; i < 14; ++i) wsrc.p[i] = (const float*)d_in[widx[i]];
  wsrc.p[14] = (const float*)d_in[18];   // Ws plain
  wsrc.p[15] = (const float*)d_in[20];   // Wx plain
  wconv<<<dim3(16, 16, 16), dim3(64, 4), 0, stream>>>(wsrc, (1u << 9) | (1u << 14) | (1u << 15), WT(0));

  {
    BiasJob j0{(const float*)d_in[19], (const float*)d_in[22], (const float*)d_in[23], nullptr, 1.f, bc_s};
    BiasJob j1{(const float*)d_in[21], (const float*)d_in[24], (const float*)d_in[25], nullptr, 1.f, bc_x};
    BiasJob j2{(const float*)d_in[27], (const float*)d_in[28], (const float*)d_in[29], (const float*)d_in[30], 2.f, bias1v};
    BiasJob j3{(const float*)d_in[27], (const float*)d_in[31], (const float*)d_in[32], (const float*)d_in[33], 2.f, bias2v};
    bias_comb<<<dim3(16, 4), 256, 0, stream>>>(j0, j1, j2, j3);
  }

  ln_bf16<<<8192, 256, 0, stream>>>(from, ln1g, ln1b, xbf, to_t, lntg, lntb, tbf, 4096);

  const int Kd = 1024;
  GOut z{};
  const int FAR = 0x7fffffff;

  // mega1 (BM=128): QKV projections + weight combines (1536 blocks, 6/CU)
  {
    Segs S{};
    S.s[0] = {xbf, WT(0), {{qh,  (const float*)d_in[9],  nullptr, QSCALE, 1},
                           {fkh, (const float*)d_in[11], nullptr, 1.f,    1}}, 3, 16, 0};
    S.s[1] = {tbf, WT(3), {{tkh, (const float*)d_in[15], nullptr, 1.f, 1}, z}, 3, 8, 512};
    S.s[2] = {WT(2), xbf, {{fvt, (const float*)d_in[13], nullptr, 1.f, 5}, z}, 5, 32, 768};
    S.s[3] = {WT(4), tbf, {{tvt, (const float*)d_in[17], nullptr, 1.f, 5}, z}, 5, 32, 1024};
    S.s[4] = {WT(7),  WT(14), {{WT(16), nullptr, nullptr, 1.f, 0}, z}, 3, 8, 1280};
    S.s[5] = {WT(8),  WT(15), {{WT(17), nullptr, nullptr, 1.f, 0}, z}, 3, 8, 1344};
    S.s[6] = {WT(10), WT(9),  {{WT(18), nullptr, nullptr, 1.f, 0}, z}, 3, 8, 1408};
    S.s[7] = {WT(11), WT(9),  {{WT(19), nullptr, nullptr, 1.f, 0}, z}, 3, 8, 1472};
    S.total = 1536;
    gemm_multi<128, 256><<<1536, 256, 0, stream>>>(S, Kd);
  }

  attn_fused<<<1024, 256, 0, stream>>>(qh, fkh, fvt, tkh, tvt, fmask, fmask, tmask, sctx, xctx);

  // quad gate: gated = (sctx@WcS+bc_s)*(xctx@Wx+bx) + (xctx@WcX+bc_x)*(sctx@Ws+bs)
  gemm_quad_gate<<<1024, 256, 0, stream>>>(sctx, xctx, WT(5), WT(6), WT(16), WT(17),
                                           (const float*)d_in[19], (const float*)d_in[21],
                                           bc_s, bc_x, gated);

  // bilinear K=2048: scores/values from {gated, xbf}, sigmoid-gate -> abf (1024 blocks)
  gemm_bilinear<<<1024, 256, 0, stream>>>(gated, xbf, WT(18), WT(10), WT(19), WT(11),
                                          bias1v, bias2v, fmask, abf);

  // G_G: abf @ Wd1 + bd1 + from -> resid (f32), BM=64, 512 blocks
  {
    Segs S{};
    S.s[0] = {abf, WT(12), {{resid, (const float*)d_in[35], from, 1.f, 3}, z}, 3, 8, 0};
    S.s[1].start = FAR; S.s[2].start = FAR; S.s[3].start = FAR;
    S.s[4].start = FAR; S.s[5].start = FAR; S.s[6].start = FAR; S.s[7].start = FAR;
    S.total = 512;
    gemm_multi<64, 256><<<512, 256, 0, stream>>>(S, Kd);
  }

  ln_bf16<<<4096, 256, 0, stream>>>(resid, ln2g, ln2b, lnr, resid, ln2g, ln2b, lnr, 4096);

  // G_H: lnr @ Wd2 + bd2 + resid -> out (f32), BM=64, 512 blocks
  {
    Segs S{};
    S.s[0] = {lnr, WT(13), {{d_out, (const float*)d_in[37], resid, 1.f, 3}, z}, 3, 8, 0};
    S.s[1].start = FAR; S.s[2].start = FAR; S.s[3].start = FAR;
    S.s[4].start = FAR; S.s[5].start = FAR; S.s[6].start = FAR; S.s[7].start = FAR;
    S.total = 512;
    gemm_multi<64, 256><<<512, 256, 0, stream>>>(S, Kd);
  }
}

// Round 10
// 428.254 us; speedup vs baseline: 1.1422x; 1.1422x over previous
//
#include <hip/hip_runtime.h>

typedef unsigned short u16;
typedef unsigned int   u32;

typedef __bf16 bf16x8 __attribute__((ext_vector_type(8)));
typedef float  f32x4  __attribute__((ext_vector_type(4)));

__device__ __forceinline__ float bf2f(u16 u) {
  union { u32 i; float f; } v; v.i = ((u32)u) << 16; return v.f;
}
__device__ __forceinline__ u16 f2bf(float f) {
  union { float f; u32 i; } v; v.f = f;
  u32 r = v.i + 0x7fffu + ((v.i >> 16) & 1u);   // RNE
  return (u16)(r >> 16);
}
__device__ __forceinline__ u32 cvtpk(float a, float b) {
  u32 r;
  asm("v_cvt_pk_bf16_f32 %0, %1, %2" : "=v"(r) : "v"(a), "v"(b));
  return r;
}

__device__ __forceinline__ f32x4 mfma16(bf16x8 a, bf16x8 b, f32x4 c) {
  return __builtin_amdgcn_mfma_f32_16x16x32_bf16(a, b, c, 0, 0, 0);
}

#define GLOAD_LDS16(gsrc, ldst) \
  __builtin_amdgcn_global_load_lds((const __attribute__((address_space(1))) void*)(gsrc), \
                                   (__attribute__((address_space(3))) void*)(ldst), 16, 0, 0)

// 0.125 * log2(e): folded into Q so softmax can use exp2
#define QSCALE 0.18033688011112042f

// B-panel row permutation (128-row panels): fragment n / lane qi covers 4
// CONSECUTIVE columns qi*4+n -> packed stores.
__device__ __forceinline__ int bperm(int slot) {
  return (slot & 64) + ((slot & 15) << 2) + ((slot >> 4) & 3);
}
// 64-row variant: fragment n (0..1) / lane qi covers 2 consecutive cols qi*2+n.
__device__ __forceinline__ int bperm64(int slot) {
  return (slot & 32) + ((slot & 15) << 1) + ((slot >> 4) & 1);
}

// ---------------- weight convert: transposed (default) or plain bf16 copy ----------------
struct W16 { const float* p[16]; };

__global__ __launch_bounds__(256)
void wconv(W16 srcs, u32 plainmask, u16* __restrict__ base)
{
  __shared__ float tile[64][65];
  const int tx = threadIdx.x;           // 0..63
  const int ty = threadIdx.y;           // 0..3
  const int n0 = blockIdx.x * 64;
  const int k0 = blockIdx.y * 64;
  // constant-index select (avoid runtime-indexed kernarg aggregate -> scratch)
  const float* W = srcs.p[0];
#pragma unroll
  for (int k = 1; k < 16; ++k) if ((int)blockIdx.z == k) W = srcs.p[k];
  u16* Wt = base + ((size_t)blockIdx.z << 20);
  if ((plainmask >> blockIdx.z) & 1u) {
#pragma unroll
    for (int j = 0; j < 16; ++j) {
      int k = k0 + ty + j * 4;
      Wt[(size_t)k * 1024 + n0 + tx] = f2bf(W[(size_t)k * 1024 + n0 + tx]);
    }
    return;
  }
#pragma unroll
  for (int j = 0; j < 16; ++j) {
    int k = ty + j * 4;
    tile[k][tx] = W[(size_t)(k0 + k) * 1024 + n0 + tx];
  }
  __syncthreads();
  const int kp = tx & 31;               // k-pair index
  const int nx = (tx >> 5) * 4;         // extra n offset
#pragma unroll
  for (int j = 0; j < 8; ++j) {
    int n = ty + nx + j * 8;
    u32 w = (u32)f2bf(tile[2 * kp][n]) | ((u32)f2bf(tile[2 * kp + 1][n]) << 16);
    ((u32*)(Wt + (size_t)(n0 + n) * 1024 + k0))[kp] = w;
  }
}

// ---------------- bias combine GEMV: out[n] = v . W[:,n] + s1*a1[n] + a2[n] ----------------
struct BiasJob { const float* v; const float* W; const float* a1; const float* a2;
                 float s1; float* out; };

__global__ __launch_bounds__(256)
void bias_comb(BiasJob j0, BiasJob j1, BiasJob j2, BiasJob j3)
{
  BiasJob J = (blockIdx.y == 0) ? j0 : (blockIdx.y == 1) ? j1 : (blockIdx.y == 2) ? j2 : j3;
  const int t = threadIdx.x;
  const int cl = t & 63;
  const int seg = t >> 6;                       // 4 K-segments of 256
  const int n = blockIdx.x * 64 + cl;           // grid.x = 16
  float acc = 0.f;
  const int jb = seg * 256;
#pragma unroll 8
  for (int j = 0; j < 256; ++j) acc += J.v[jb + j] * J.W[(size_t)(jb + j) * 1024 + n];
  __shared__ float red[4][64];
  red[seg][cl] = acc;
  __syncthreads();
  if (seg == 0) {
    float r = red[0][cl] + red[1][cl] + red[2][cl] + red[3][cl]
            + J.s1 * J.a1[n] + (J.a2 ? J.a2[n] : 0.f);
    J.out[n] = r;
  }
}

// ---------------- LayerNorm (row = 1024) -> bf16, dual source ----------------
__global__ __launch_bounds__(256)
void ln_bf16(const float* __restrict__ in0, const float* __restrict__ g0,
             const float* __restrict__ b0, u16* __restrict__ out0,
             const float* __restrict__ in1, const float* __restrict__ g1,
             const float* __restrict__ b1, u16* __restrict__ out1, int split)
{
  int row = blockIdx.x;
  const float *in, *gw, *bw; u16* out;
  if (row < split) { in = in0; gw = g0; bw = b0; out = out0; }
  else             { in = in1; gw = g1; bw = b1; out = out1; row -= split; }
  const int t = threadIdx.x;
  const float4 v = ((const float4*)(in + (size_t)row * 1024))[t];
  float s  = v.x + v.y + v.z + v.w;
  float sq = v.x*v.x + v.y*v.y + v.z*v.z + v.w*v.w;
#pragma unroll
  for (int o = 32; o >= 1; o >>= 1) {
    s  += __shfl_xor(s, o);
    sq += __shfl_xor(sq, o);
  }
  __shared__ float red[8];
  const int wv = t >> 6;
  if ((t & 63) == 0) { red[wv] = s; red[4 + wv] = sq; }
  __syncthreads();
  s  = red[0] + red[1] + red[2] + red[3];
  sq = red[4] + red[5] + red[6] + red[7];
  const float mean = s * (1.f / 1024.f);
  const float var  = sq * (1.f / 1024.f) - mean * mean;
  const float rstd = rsqrtf(var + 1e-6f);
  const float4 g4 = ((const float4*)gw)[t];
  const float4 b4 = ((const float4*)bw)[t];
  uint2 w;
  w.x = cvtpk((v.x - mean) * rstd * g4.x + b4.x, (v.y - mean) * rstd * g4.y + b4.y);
  w.y = cvtpk((v.z - mean) * rstd * g4.z + b4.z, (v.w - mean) * rstd * g4.w + b4.w);
  ((uint2*)(out + (size_t)row * 1024))[t] = w;
}

// ---------------- segmented GEMM: C = A[M,K](bf16) @ Bt[N,K](bf16)^T ----------------
// modes: 0 bf16 row-major; 1 bf16 [B,H,L,HD]; 3 f32 (+f32 res); 4 bf16 (+bf16 res);
// 5 V-transposed (A=weight rows, Bt=activation rows), bias indexed by ROW.
struct GOut { void* ptr; const float* bias; const void* res; float oscale; int mode; };
struct Seg  { const u16* A; const u16* Bt; GOut od[2]; int odshift; int gx; int start; };
struct Segs { Seg s[8]; int total; };

template<int BM, int TPB>
__global__ __launch_bounds__(TPB)
void gemm_multi(Segs S, int K)
{
  constexpr int NW   = TPB / 64;        // waves per block
  constexpr int ROWG = NW / 2;          // row wave-groups (2 col groups)
  constexpr int WM   = BM / ROWG;       // rows per wave
  constexpr int MF   = WM / 16;         // m-fragments per wave
  constexpr int nA   = BM / 8;          // A chunks
  constexpr int PW   = (nA + 16) / NW;  // chunks per wave
  __shared__ u16 As[BM * 64];
  __shared__ u16 Bs[128 * 64];
  const int t    = threadIdx.x;
  const int lane = t & 63;
  const int wave = t >> 6;
  const int qi   = lane & 15;
  const int g    = lane >> 4;
  const int cpx  = S.total >> 3;        // XCD swizzle (total % 8 == 0)
  const int flat = blockIdx.x;
  const int nid  = (flat & 7) * cpx + (flat >> 3);
  // constant-index segment select (rule #20: no runtime-indexed aggregate)
  Seg sg = S.s[0];
#pragma unroll
  for (int k = 1; k < 8; ++k) { Seg c = S.s[k]; if (nid >= c.start) sg = c; }
  const int local = nid - sg.start;
  const int bx = local % sg.gx;
  const int by = local / sg.gx;
  const int row0 = by * BM;
  const int col0 = bx * 128;
  const int wrow = (wave >> 1) * WM;
  const int wcol = (wave & 1) * 64;

  f32x4 acc[MF][4] = {};

  const int srow  = lane >> 3;
  const int skseg = (lane & 7) * 8;
  const u16* A  = sg.A;
  const u16* Bt = sg.Bt;

  for (int kt = 0; kt < K; kt += 64) {
    __syncthreads();
#pragma unroll
    for (int i = 0; i < PW; ++i) {
      int chunk = wave * PW + i;
      if (chunk < nA) {
        GLOAD_LDS16(A + (size_t)(row0 + chunk * 8 + srow) * K + kt + skseg, As + chunk * 512);
      } else {
        int cb = chunk - nA;
        int grow = bperm(cb * 8 + srow);
        GLOAD_LDS16(Bt + (size_t)(col0 + grow) * K + kt + skseg, Bs + cb * 512);
      }
    }
    __syncthreads();
#pragma unroll
    for (int kk = 0; kk < 2; ++kk) {
      bf16x8 af[MF], bfv[4];
#pragma unroll
      for (int m = 0; m < MF; ++m)
        af[m] = *(const bf16x8*)(As + (wrow + m * 16 + qi) * 64 + kk * 32 + g * 8);
#pragma unroll
      for (int n = 0; n < 4; ++n)
        bfv[n] = *(const bf16x8*)(Bs + (wcol + n * 16 + qi) * 64 + kk * 32 + g * 8);
#pragma unroll
      for (int m = 0; m < MF; ++m)
#pragma unroll
        for (int n = 0; n < 4; ++n)
          acc[m][n] = mfma16(af[m], bfv[n], acc[m][n]);
    }
  }

  // constant-index output-descriptor select
  GOut od = sg.od[0];
  if ((bx >> sg.odshift) != 0) od = sg.od[1];
  const int cbase = (bx & ((1 << sg.odshift) - 1)) * 128 + wcol;
  const int c0 = cbase + (qi << 2);     // 4 consecutive output cols per lane
  float4 b4; b4.x = b4.y = b4.z = b4.w = 0.f;
  if (od.mode != 5 && od.bias) b4 = *(const float4*)(od.bias + c0);
#pragma unroll
  for (int m = 0; m < MF; ++m) {
#pragma unroll
    for (int j = 0; j < 4; ++j) {
      const int row = row0 + wrow + m * 16 + g * 4 + j;
      float v0 = (acc[m][0][j] + b4.x) * od.oscale;
      float v1 = (acc[m][1][j] + b4.y) * od.oscale;
      float v2 = (acc[m][2][j] + b4.z) * od.oscale;
      float v3 = (acc[m][3][j] + b4.w) * od.oscale;
      if (od.mode == 0) {
        uint2 w; w.x = cvtpk(v0, v1); w.y = cvtpk(v2, v3);
        *(uint2*)((u16*)od.ptr + (size_t)row * 1024 + c0) = w;
      } else if (od.mode == 1) {
        int bb = row >> 9, l = row & 511, hh = c0 >> 6, hd = c0 & 63;
        uint2 w; w.x = cvtpk(v0, v1); w.y = cvtpk(v2, v3);
        *(uint2*)((u16*)od.ptr + (((size_t)(bb * 16 + hh) * 512) + l) * 64 + hd) = w;
      } else if (od.mode == 5) {
        float br = od.bias[row];
        int hh = row >> 6, hd = row & 63, bb = c0 >> 9, l0 = c0 & 511;
        uint2 w; w.x = cvtpk(v0 + br, v1 + br); w.y = cvtpk(v2 + br, v3 + br);
        *(uint2*)((u16*)od.ptr + (((size_t)(bb * 16 + hh) * 64) + hd) * 512 + l0) = w;
      } else if (od.mode == 3) {
        float4 o; o.x = v0; o.y = v1; o.z = v2; o.w = v3;
        if (od.res) {
          const float4 r4 = *(const float4*)((const float*)od.res + (size_t)row * 1024 + c0);
          o.x += r4.x; o.y += r4.y; o.z += r4.z; o.w += r4.w;
        }
        *(float4*)((float*)od.ptr + (size_t)row * 1024 + c0) = o;
      } else { // 4: bf16 + bf16 res
        uint2 r = *(const uint2*)((const u16*)od.res + (size_t)row * 1024 + c0);
        uint2 w;
        w.x = cvtpk(v0 + bf2f((u16)(r.x & 0xffffu)), v1 + bf2f((u16)(r.x >> 16)));
        w.y = cvtpk(v2 + bf2f((u16)(r.y & 0xffffu)), v3 + bf2f((u16)(r.y >> 16)));
        *(uint2*)((u16*)od.ptr + (size_t)row * 1024 + c0) = w;
      }
    }
  }
}

// ---------------- quad gate GEMM (4 GEMMs + gate), BM=128/BN=64, 512 blocks ------
// gated = (sctx@WcS+bcs)*(xctx@Wx+bx) + (xctx@WcX+bcx)*(sctx@Ws+bs)
__global__ __launch_bounds__(256)
void gemm_quad_gate(const u16* __restrict__ A1, const u16* __restrict__ A2,
                    const u16* __restrict__ BWs, const u16* __restrict__ BWx,
                    const u16* __restrict__ BWcs, const u16* __restrict__ BWcx,
                    const float* __restrict__ bs, const float* __restrict__ bx,
                    const float* __restrict__ bcs, const float* __restrict__ bcx,
                    u16* __restrict__ out)
{
  __shared__ u16 As1[128 * 64];
  __shared__ u16 As2[128 * 64];
  __shared__ u16 Bs0[64 * 64];
  __shared__ u16 Bs1[64 * 64];
  __shared__ u16 Bs2[64 * 64];
  __shared__ u16 Bs3[64 * 64];
  const int t    = threadIdx.x;
  const int lane = t & 63;
  const int wave = t >> 6;
  const int qi   = lane & 15;
  const int g    = lane >> 4;
  const int flat = blockIdx.x;                  // 512 blocks
  const int nid  = (flat & 7) * 64 + (flat >> 3);
  const int bxi  = nid & 15;                    // 16 col-blocks of 64
  const int byi  = nid >> 4;                    // 32 row-blocks of 128
  const int row0 = byi * 128;
  const int col0 = bxi * 64;
  const int wrow = (wave >> 1) * 64;
  const int wcol = (wave & 1) * 32;

  f32x4 aS1[4][2] = {}, aX1[4][2] = {}, aS2[4][2] = {}, aX2[4][2] = {};

  const int srow  = lane >> 3;
  const int skseg = (lane & 7) * 8;

  for (int kt = 0; kt < 1024; kt += 64) {
    __syncthreads();
#pragma unroll
    for (int i = 0; i < 16; ++i) {
      int chunk = wave * 16 + i;                // 0..63
      if (chunk < 16) {
        GLOAD_LDS16(A1 + (size_t)(row0 + chunk * 8 + srow) * 1024 + kt + skseg, As1 + chunk * 512);
      } else if (chunk < 32) {
        int cb = chunk - 16;
        GLOAD_LDS16(A2 + (size_t)(row0 + cb * 8 + srow) * 1024 + kt + skseg, As2 + cb * 512);
      } else {
        int w2 = chunk - 32;
        int cb = w2 & 7;
        int grow = bperm64(cb * 8 + srow);
        const size_t goff = (size_t)(col0 + grow) * 1024 + kt + skseg;
        if (w2 < 8)       { GLOAD_LDS16(BWs  + goff, Bs0 + cb * 512); }
        else if (w2 < 16) { GLOAD_LDS16(BWx  + goff, Bs1 + cb * 512); }
        else if (w2 < 24) { GLOAD_LDS16(BWcs + goff, Bs2 + cb * 512); }
        else              { GLOAD_LDS16(BWcx + goff, Bs3 + cb * 512); }
      }
    }
    __syncthreads();
#pragma unroll
    for (int kk = 0; kk < 2; ++kk) {
      bf16x8 a1[4], a2[4], b0[2], b1[2], b2[2], b3[2];
#pragma unroll
      for (int m = 0; m < 4; ++m) {
        a1[m] = *(const bf16x8*)(As1 + (wrow + m * 16 + qi) * 64 + kk * 32 + g * 8);
        a2[m] = *(const bf16x8*)(As2 + (wrow + m * 16 + qi) * 64 + kk * 32 + g * 8);
      }
#pragma unroll
      for (int n = 0; n < 2; ++n) {
        const int ro = (wcol + n * 16 + qi) * 64 + kk * 32 + g * 8;
        b0[n] = *(const bf16x8*)(Bs0 + ro);
        b1[n] = *(const bf16x8*)(Bs1 + ro);
        b2[n] = *(const bf16x8*)(Bs2 + ro);
        b3[n] = *(const bf16x8*)(Bs3 + ro);
      }
#pragma unroll
      for (int m = 0; m < 4; ++m)
#pragma unroll
        for (int n = 0; n < 2; ++n) {
          aS1[m][n] = mfma16(a1[m], b0[n], aS1[m][n]);
          aX1[m][n] = mfma16(a2[m], b1[n], aX1[m][n]);
          aS2[m][n] = mfma16(a1[m], b2[n], aS2[m][n]);
          aX2[m][n] = mfma16(a2[m], b3[n], aX2[m][n]);
        }
    }
  }

  const int c0 = col0 + wcol + (qi << 1);       // 2 consecutive cols per lane
  const float2 vbs  = *(const float2*)(bs  + c0);
  const float2 vbx  = *(const float2*)(bx  + c0);
  const float2 vbcs = *(const float2*)(bcs + c0);
  const float2 vbcx = *(const float2*)(bcx + c0);
#pragma unroll
  for (int m = 0; m < 4; ++m) {
#pragma unroll
    for (int j = 0; j < 4; ++j) {
      const int row = row0 + wrow + m * 16 + g * 4 + j;
      float sv0 = aS1[m][0][j] + vbs.x,  sv1 = aS1[m][1][j] + vbs.y;
      float xv0 = aX1[m][0][j] + vbx.x,  xv1 = aX1[m][1][j] + vbx.y;
      float sg0 = aS2[m][0][j] + vbcs.x, sg1 = aS2[m][1][j] + vbcs.y;
      float xg0 = aX2[m][0][j] + vbcx.x, xg1 = aX2[m][1][j] + vbcx.y;
      u32 w = cvtpk(sg0 * xv0 + xg0 * sv0, sg1 * xv1 + xg1 * sv1);
      *(u32*)(out + (size_t)row * 1024 + c0) = w;
    }
  }
}

// ---------------- bilinear K=2048 (virtual concat), BM=128/BN=64, 512 blocks ------
__global__ __launch_bounds__(256)
void gemm_bilinear(const u16* __restrict__ A1, const u16* __restrict__ A2,
                   const u16* __restrict__ B1a, const u16* __restrict__ B1b,
                   const u16* __restrict__ B2a, const u16* __restrict__ B2b,
                   const float* __restrict__ bias1, const float* __restrict__ bias2,
                   const int* __restrict__ fm, u16* __restrict__ out)
{
  __shared__ u16 As[128 * 64];
  __shared__ u16 B1s[64 * 64];
  __shared__ u16 B2s[64 * 64];
  const int t    = threadIdx.x;
  const int lane = t & 63;
  const int wave = t >> 6;
  const int qi   = lane & 15;
  const int g    = lane >> 4;
  const int flat = blockIdx.x;                  // 512 blocks
  const int nid  = (flat & 7) * 64 + (flat >> 3);
  const int bxi  = nid & 15;                    // 16 col-blocks of 64
  const int byi  = nid >> 4;                    // 32 row-blocks of 128
  const int row0 = byi * 128;
  const int col0 = bxi * 64;
  const int wrow = (wave >> 1) * 64;
  const int wcol = (wave & 1) * 32;

  f32x4 accS[4][2] = {};
  f32x4 accV[4][2] = {};

  const int srow  = lane >> 3;
  const int skseg = (lane & 7) * 8;

  for (int kt = 0; kt < 2048; kt += 64) {
    const u16* Ap  = (kt < 1024) ? A1  : A2;
    const u16* B1p = (kt < 1024) ? B1a : B1b;
    const u16* B2p = (kt < 1024) ? B2a : B2b;
    const int kto = kt & 1023;
    __syncthreads();
#pragma unroll
    for (int i = 0; i < 8; ++i) {
      int chunk = wave * 8 + i;                 // 0..31
      if (chunk < 16) {
        GLOAD_LDS16(Ap + (size_t)(row0 + chunk * 8 + srow) * 1024 + kto + skseg, As + chunk * 512);
      } else if (chunk < 24) {
        int cb = chunk - 16;
        int grow = bperm64(cb * 8 + srow);
        GLOAD_LDS16(B1p + (size_t)(col0 + grow) * 1024 + kto + skseg, B1s + cb * 512);
      } else {
        int cb = chunk - 24;
        int grow = bperm64(cb * 8 + srow);
        GLOAD_LDS16(B2p + (size_t)(col0 + grow) * 1024 + kto + skseg, B2s + cb * 512);
      }
    }
    __syncthreads();
#pragma unroll
    for (int kk = 0; kk < 2; ++kk) {
      bf16x8 af[4], b1[2], b2[2];
#pragma unroll
      for (int m = 0; m < 4; ++m)
        af[m] = *(const bf16x8*)(As + (wrow + m * 16 + qi) * 64 + kk * 32 + g * 8);
#pragma unroll
      for (int n = 0; n < 2; ++n) {
        const int ro = (wcol + n * 16 + qi) * 64 + kk * 32 + g * 8;
        b1[n] = *(const bf16x8*)(B1s + ro);
        b2[n] = *(const bf16x8*)(B2s + ro);
      }
#pragma unroll
      for (int m = 0; m < 4; ++m)
#pragma unroll
        for (int n = 0; n < 2; ++n) {
          accS[m][n] = mfma16(af[m], b1[n], accS[m][n]);
          accV[m][n] = mfma16(af[m], b2[n], accV[m][n]);
        }
    }
  }

  const int c0 = col0 + wcol + (qi << 1);
  const float2 b1v = *(const float2*)(bias1 + c0);
  const float2 b2v = *(const float2*)(bias2 + c0);
#pragma unroll
  for (int m = 0; m < 4; ++m) {
#pragma unroll
    for (int j = 0; j < 4; ++j) {
      const int row = row0 + wrow + m * 16 + g * 4 + j;
      const float neg = fm[row] ? 0.f : -1e30f;
      float s0 = accS[m][0][j] + b1v.x + neg;
      float s1 = accS[m][1][j] + b1v.y + neg;
      float o0 = (1.f / (1.f + expf(-s0))) * (accV[m][0][j] + b2v.x);
      float o1 = (1.f / (1.f + expf(-s1))) * (accV[m][1][j] + b2v.y);
      *(u32*)(out + (size_t)row * 1024 + c0) = cvtpk(o0, o1);
    }
  }
}

// ---------------- fused flash attention: fixed-shift softmax, 2 q-chains/wave ----
__global__ __launch_bounds__(256)
void attn_fused(const u16* __restrict__ Q,
                const u16* __restrict__ K0, const u16* __restrict__ V0,
                const u16* __restrict__ K1, const u16* __restrict__ V1,
                const int* __restrict__ qmask,
                const int* __restrict__ km0, const int* __restrict__ km1,
                u16* __restrict__ ctx0, u16* __restrict__ ctx1)
{
  const int T = 512, L = 512;
  const int lane = threadIdx.x & 63;
  const int wave = threadIdx.x >> 6;
  const int qi = lane & 15;
  const int g  = lane >> 4;
  const int bid = blockIdx.x;               // 0..1023
  const int z   = bid >> 9;
  const int ib  = bid & 511;
  const int xcd = ib & 7;
  const int iw  = ib >> 3;                  // 0..63
  const int bh  = xcd * 16 + (iw & 15);
  const int qblk = iw >> 4;                 // 0..3
  const int b  = bh >> 4;
  const int h  = bh & 15;
  const int q0a = qblk * 128 + wave * 16;
  const int q0b = q0a + 64;

  const u16* Kh = z ? K1 : K0;
  const u16* Vt = z ? V1 : V0;
  const int* kmb = (z ? km1 : km0) + b * T;
  u16* ctx = z ? ctx1 : ctx0;

  __shared__ u16 Plds[4][2][16 * 136];      // per-wave, per-chain P^T bounce
  u16* Pa = Plds[wave][0];
  u16* Pb = Plds[wave][1];

  const size_t qoffa = ((size_t)bh * L + q0a + qi) * 64;
  const size_t qoffb = ((size_t)bh * L + q0b + qi) * 64;
  const bf16x8 qa0 = *(const bf16x8*)(Q + qoffa + g * 8);
  const bf16x8 qa1 = *(const bf16x8*)(Q + qoffa + 32 + g * 8);
  const bf16x8 qb0 = *(const bf16x8*)(Q + qoffb + g * 8);
  const bf16x8 qb1 = *(const bf16x8*)(Q + qoffb + 32 + g * 8);

  const float qma = (float)qmask[b * L + q0a + qi];
  const float qmb = (float)qmask[b * L + q0b + qi];
  float tsa = 0.f, tsb = 0.f;
  f32x4 ofa[4] = {}, ofb[4] = {};

  for (int kb = 0; kb < T; kb += 128) {     // 4 iterations
    f32x4 sta[8], stb[8];
    __builtin_amdgcn_s_setprio(1);
#pragma unroll
    for (int s = 0; s < 8; ++s) {
      const size_t koff = ((size_t)bh * T + kb + s * 16 + qi) * 64;
      bf16x8 k0v = *(const bf16x8*)(Kh + koff + g * 8);
      bf16x8 k1v = *(const bf16x8*)(Kh + koff + 32 + g * 8);
      f32x4 za = {}; za = mfma16(k0v, qa0, za); sta[s] = mfma16(k1v, qa1, za);
      f32x4 zb = {}; zb = mfma16(k0v, qb0, zb); stb[s] = mfma16(k1v, qb1, zb);
    }
    __builtin_amdgcn_s_setprio(0);
#pragma unroll
    for (int s = 0; s < 8; ++s) {
      int4 km4 = *(const int4*)(kmb + kb + s * 16 + g * 4);
      const float m0 = km4.x ? 0.f : -1e30f;
      const float m1 = km4.y ? 0.f : -1e30f;
      const float m2 = km4.z ? 0.f : -1e30f;
      const float m3 = km4.w ? 0.f : -1e30f;
      float a0 = exp2f(fmaf(sta[s][0] + m0, qma, -20.f));
      float a1 = exp2f(fmaf(sta[s][1] + m1, qma, -20.f));
      float a2 = exp2f(fmaf(sta[s][2] + m2, qma, -20.f));
      float a3 = exp2f(fmaf(sta[s][3] + m3, qma, -20.f));
      tsa += (a0 + a1) + (a2 + a3);
      uint2 wa; wa.x = cvtpk(a0, a1); wa.y = cvtpk(a2, a3);
      *(uint2*)(Pa + qi * 136 + s * 16 + g * 4) = wa;
      float p0 = exp2f(fmaf(stb[s][0] + m0, qmb, -20.f));
      float p1 = exp2f(fmaf(stb[s][1] + m1, qmb, -20.f));
      float p2 = exp2f(fmaf(stb[s][2] + m2, qmb, -20.f));
      float p3 = exp2f(fmaf(stb[s][3] + m3, qmb, -20.f));
      tsb += (p0 + p1) + (p2 + p3);
      uint2 wb; wb.x = cvtpk(p0, p1); wb.y = cvtpk(p2, p3);
      *(uint2*)(Pb + qi * 136 + s * 16 + g * 4) = wb;
    }
    bf16x8 paf[4], pbf[4];
#pragma unroll
    for (int ks = 0; ks < 4; ++ks) {
      paf[ks] = *(const bf16x8*)(Pa + qi * 136 + ks * 32 + g * 8);
      pbf[ks] = *(const bf16x8*)(Pb + qi * 136 + ks * 32 + g * 8);
    }
    __builtin_amdgcn_s_setprio(1);
#pragma unroll
    for (int nf = 0; nf < 4; ++nf) {
      f32x4 oa = ofa[nf], ob = ofb[nf];
#pragma unroll
      for (int ks = 0; ks < 4; ++ks) {
        const size_t voff = ((size_t)bh * 64 + nf * 16 + qi) * (size_t)T + kb + ks * 32 + g * 8;
        bf16x8 vb = *(const bf16x8*)(Vt + voff);
        oa = mfma16(paf[ks], vb, oa);
        ob = mfma16(pbf[ks], vb, ob);
      }
      ofa[nf] = oa; ofb[nf] = ob;
    }
    __builtin_amdgcn_s_setprio(0);
  }
  tsa += __shfl_xor(tsa, 16); tsa += __shfl_xor(tsa, 32);
  tsb += __shfl_xor(tsb, 16); tsb += __shfl_xor(tsb, 32);
  const float lia = 1.f / tsa;
  const float lib = 1.f / tsb;
  float lja[4], ljb[4];
#pragma unroll
  for (int j = 0; j < 4; ++j) {
    lja[j] = __shfl(lia, g * 4 + j);
    ljb[j] = __shfl(lib, g * 4 + j);
  }
#pragma unroll
  for (int nf = 0; nf < 4; ++nf) {
    int col = h * 64 + nf * 16 + qi;
#pragma unroll
    for (int j = 0; j < 4; ++j) {
      int rowa = q0a + g * 4 + j;
      int rowb = q0b + g * 4 + j;
      ctx[((size_t)b * L + rowa) * 1024 + col] = f2bf(ofa[nf][j] * lja[j]);
      ctx[((size_t)b * L + rowb) * 1024 + col] = f2bf(ofb[nf][j] * ljb[j]);
    }
  }
}

// ---------------- driver ----------------
extern "C" void kernel_launch(void* const* d_in, const int* in_sizes, int n_in,
                              void* d_out, int out_size, void* d_ws, size_t ws_size,
                              hipStream_t stream)
{
  (void)in_sizes; (void)n_in; (void)out_size; (void)ws_size;
  const float* from = (const float*)d_in[0];
  const float* to_t = (const float*)d_in[1];
  const float* ln1g = (const float*)d_in[2];
  const float* ln1b = (const float*)d_in[3];
  const float* lntg = (const float*)d_in[4];
  const float* lntb = (const float*)d_in[5];
  const float* ln2g = (const float*)d_in[6];
  const float* ln2b = (const float*)d_in[7];
  const int* fmask = (const int*)d_in[38];
  const int* tmask = (const int*)d_in[39];

  char* ws = (char*)d_ws;
  const size_t MB = 1ull << 20;
  auto WT = [&](int i) { return (u16*)(ws + (size_t)i * 2 * MB); };   // slots 0..19 (40MB)
  // WT: 0 Wq^T 1 Wfk^T 2 Wfv^T 3 Wtk^T 4 Wtv^T 5 Ws^T 6 Wx^T 7 Wsg^T 8 Wxg^T
  //     9 Wg(plain) 10 W1^T 11 W2^T 12 Wd1^T 13 Wd2^T 14 Ws(plain) 15 Wx(plain)
  //     16 WcS^T=(Ws@Wsg)^T 17 WcX^T 18 WcG1^T=(Wg@W1)^T 19 WcG2^T
  float* bc_s   = (float*)(ws + 40 * MB);
  float* bc_x   = bc_s + 1024;
  float* bias1v = bc_s + 2048;
  float* bias2v = bc_s + 3072;
  u16*   xbf    = (u16*)(ws + 42 * MB);
  u16*   tbf    = (u16*)(ws + 50 * MB);
  u16*   qh     = (u16*)(ws + 58 * MB);
  u16*   fkh    = (u16*)(ws + 66 * MB);
  u16*   fvt    = (u16*)(ws + 74 * MB);
  u16*   tkh    = (u16*)(ws + 82 * MB);
  u16*   tvt    = (u16*)(ws + 90 * MB);
  u16*   xctx   = (u16*)(ws + 98 * MB);
  // temporally-disjoint reuse:
  u16*   sctx   = (u16*)(ws + 50 * MB);         // over tbf (dead after mega1)
  u16*   gated  = (u16*)(ws + 90 * MB);         // over tvt (dead after attn)
  u16*   abf    = (u16*)(ws + 98 * MB);         // over xctx (dead after quad)
  float* resid  = (float*)(ws + 58 * MB);       // 16MB over qh/fkh (dead after bilinear)
  u16*   lnr    = (u16*)(ws + 74 * MB);         // over fvt (dead)

  W16 wsrc;
  const int widx[14] = {8, 10, 12, 14, 16, 18, 20, 22, 24, 26, 28, 31, 34, 36};
  for (int i = 0; i < 14; ++i) wsrc.p[i] = (const float*)d_in[widx[i]];
  wsrc.p[14] = (const float*)d_in[18];   // Ws plain
  wsrc.p[15] = (const float*)d_in[20];   // Wx plain
  wconv<<<dim3(16, 16, 16), dim3(64, 4), 0, stream>>>(wsrc, (1u << 9) | (1u << 14) | (1u << 15), WT(0));

  {
    BiasJob j0{(const float*)d_in[19], (const float*)d_in[22], (const float*)d_in[23], nullptr, 1.f, bc_s};
    BiasJob j1{(const float*)d_in[21], (const float*)d_in[24], (const float*)d_in[25], nullptr, 1.f, bc_x};
    BiasJob j2{(const float*)d_in[27], (const float*)d_in[28], (const float*)d_in[29], (const float*)d_in[30], 2.f, bias1v};
    BiasJob j3{(const float*)d_in[27], (const float*)d_in[31], (const float*)d_in[32], (const float*)d_in[33], 2.f, bias2v};
    bias_comb<<<dim3(16, 4), 256, 0, stream>>>(j0, j1, j2, j3);
  }

  ln_bf16<<<8192, 256, 0, stream>>>(from, ln1g, ln1b, xbf, to_t, lntg, lntb, tbf, 4096);

  const int Kd = 1024;
  GOut z{};
  const int FAR = 0x7fffffff;

  // mega1 (BM=128): QKV projections + weight combines (1536 blocks, 6/CU)
  {
    Segs S{};
    S.s[0] = {xbf, WT(0), {{qh,  (const float*)d_in[9],  nullptr, QSCALE, 1},
                           {fkh, (const float*)d_in[11], nullptr, 1.f,    1}}, 3, 16, 0};
    S.s[1] = {tbf, WT(3), {{tkh, (const float*)d_in[15], nullptr, 1.f, 1}, z}, 3, 8, 512};
    S.s[2] = {WT(2), xbf, {{fvt, (const float*)d_in[13], nullptr, 1.f, 5}, z}, 5, 32, 768};
    S.s[3] = {WT(4), tbf, {{tvt, (const float*)d_in[17], nullptr, 1.f, 5}, z}, 5, 32, 1024};
    S.s[4] = {WT(7),  WT(14), {{WT(16), nullptr, nullptr, 1.f, 0}, z}, 3, 8, 1280};
    S.s[5] = {WT(8),  WT(15), {{WT(17), nullptr, nullptr, 1.f, 0}, z}, 3, 8, 1344};
    S.s[6] = {WT(10), WT(9),  {{WT(18), nullptr, nullptr, 1.f, 0}, z}, 3, 8, 1408};
    S.s[7] = {WT(11), WT(9),  {{WT(19), nullptr, nullptr, 1.f, 0}, z}, 3, 8, 1472};
    S.total = 1536;
    gemm_multi<128, 256><<<1536, 256, 0, stream>>>(S, Kd);
  }

  attn_fused<<<1024, 256, 0, stream>>>(qh, fkh, fvt, tkh, tvt, fmask, fmask, tmask, sctx, xctx);

  // quad gate: gated = (sctx@WcS+bc_s)*(xctx@Wx+bx) + (xctx@WcX+bc_x)*(sctx@Ws+bs)
  gemm_quad_gate<<<512, 256, 0, stream>>>(sctx, xctx, WT(5), WT(6), WT(16), WT(17),
                                          (const float*)d_in[19], (const float*)d_in[21],
                                          bc_s, bc_x, gated);

  // bilinear K=2048: scores/values from {gated, xbf}, sigmoid-gate -> abf (512 blocks)
  gemm_bilinear<<<512, 256, 0, stream>>>(gated, xbf, WT(18), WT(10), WT(19), WT(11),
                                         bias1v, bias2v, fmask, abf);

  // G_G: abf @ Wd1 + bd1 + from -> resid (f32), BM=64, 512 blocks
  {
    Segs S{};
    S.s[0] = {abf, WT(12), {{resid, (const float*)d_in[35], from, 1.f, 3}, z}, 3, 8, 0};
    S.s[1].start = FAR; S.s[2].start = FAR; S.s[3].start = FAR;
    S.s[4].start = FAR; S.s[5].start = FAR; S.s[6].start = FAR; S.s[7].start = FAR;
    S.total = 512;
    gemm_multi<64, 256><<<512, 256, 0, stream>>>(S, Kd);
  }

  ln_bf16<<<4096, 256, 0, stream>>>(resid, ln2g, ln2b, lnr, resid, ln2g, ln2b, lnr, 4096);

  // G_H: lnr @ Wd2 + bd2 + resid -> out (f32), BM=64, 512 blocks
  {
    Segs S{};
    S.s[0] = {lnr, WT(13), {{d_out, (const float*)d_in[37], resid, 1.f, 3}, z}, 3, 8, 0};
    S.s[1].start = FAR; S.s[2].start = FAR; S.s[3].start = FAR;
    S.s[4].start = FAR; S.s[5].start = FAR; S.s[6].start = FAR; S.s[7].start = FAR;
    S.total = 512;
    gemm_multi<64, 256><<<512, 256, 0, stream>>>(S, Kd);
  }
}

// Round 11
// 410.964 us; speedup vs baseline: 1.1903x; 1.0421x over previous
//
#include <hip/hip_runtime.h>

typedef unsigned short u16;
typedef unsigned int   u32;

typedef __bf16 bf16x8 __attribute__((ext_vector_type(8)));
typedef float  f32x4  __attribute__((ext_vector_type(4)));

__device__ __forceinline__ float bf2f(u16 u) {
  union { u32 i; float f; } v; v.i = ((u32)u) << 16; return v.f;
}
__device__ __forceinline__ u16 f2bf(float f) {
  union { float f; u32 i; } v; v.f = f;
  u32 r = v.i + 0x7fffu + ((v.i >> 16) & 1u);   // RNE
  return (u16)(r >> 16);
}
__device__ __forceinline__ u32 cvtpk(float a, float b) {
  u32 r;
  asm("v_cvt_pk_bf16_f32 %0, %1, %2" : "=v"(r) : "v"(a), "v"(b));
  return r;
}

__device__ __forceinline__ f32x4 mfma16(bf16x8 a, bf16x8 b, f32x4 c) {
  return __builtin_amdgcn_mfma_f32_16x16x32_bf16(a, b, c, 0, 0, 0);
}

#define GLOAD_LDS16(gsrc, ldst) \
  __builtin_amdgcn_global_load_lds((const __attribute__((address_space(1))) void*)(gsrc), \
                                   (__attribute__((address_space(3))) void*)(ldst), 16, 0, 0)

// 0.125 * log2(e): folded into Q so softmax can use exp2
#define QSCALE 0.18033688011112042f

// B-panel row permutation (128-row panels): fragment n / lane qi covers 4
// CONSECUTIVE columns qi*4+n -> packed stores.
__device__ __forceinline__ int bperm(int slot) {
  return (slot & 64) + ((slot & 15) << 2) + ((slot >> 4) & 3);
}
// 64-row variant: fragment n (0..1) / lane qi covers 2 consecutive cols qi*2+n.
__device__ __forceinline__ int bperm64(int slot) {
  return (slot & 32) + ((slot & 15) << 1) + ((slot >> 4) & 1);
}

// ---------------- weight convert: transposed (default) or plain bf16 copy ----------------
struct W16 { const float* p[16]; };

__global__ __launch_bounds__(256)
void wconv(W16 srcs, u32 plainmask, u16* __restrict__ base)
{
  __shared__ float tile[64][65];
  const int tx = threadIdx.x;           // 0..63
  const int ty = threadIdx.y;           // 0..3
  const int n0 = blockIdx.x * 64;
  const int k0 = blockIdx.y * 64;
  // constant-index select (avoid runtime-indexed kernarg aggregate -> scratch)
  const float* W = srcs.p[0];
#pragma unroll
  for (int k = 1; k < 16; ++k) if ((int)blockIdx.z == k) W = srcs.p[k];
  u16* Wt = base + ((size_t)blockIdx.z << 20);
  if ((plainmask >> blockIdx.z) & 1u) {
#pragma unroll
    for (int j = 0; j < 16; ++j) {
      int k = k0 + ty + j * 4;
      Wt[(size_t)k * 1024 + n0 + tx] = f2bf(W[(size_t)k * 1024 + n0 + tx]);
    }
    return;
  }
#pragma unroll
  for (int j = 0; j < 16; ++j) {
    int k = ty + j * 4;
    tile[k][tx] = W[(size_t)(k0 + k) * 1024 + n0 + tx];
  }
  __syncthreads();
  const int kp = tx & 31;               // k-pair index
  const int nx = (tx >> 5) * 4;         // extra n offset
#pragma unroll
  for (int j = 0; j < 8; ++j) {
    int n = ty + nx + j * 8;
    u32 w = (u32)f2bf(tile[2 * kp][n]) | ((u32)f2bf(tile[2 * kp + 1][n]) << 16);
    ((u32*)(Wt + (size_t)(n0 + n) * 1024 + k0))[kp] = w;
  }
}

// ---------------- bias combine GEMV: out[n] = v . W[:,n] + s1*a1[n] + a2[n] ----------------
struct BiasJob { const float* v; const float* W; const float* a1; const float* a2;
                 float s1; float* out; };

__global__ __launch_bounds__(256)
void bias_comb(BiasJob j0, BiasJob j1, BiasJob j2, BiasJob j3)
{
  BiasJob J = (blockIdx.y == 0) ? j0 : (blockIdx.y == 1) ? j1 : (blockIdx.y == 2) ? j2 : j3;
  const int t = threadIdx.x;
  const int cl = t & 63;
  const int seg = t >> 6;                       // 4 K-segments of 256
  const int n = blockIdx.x * 64 + cl;           // grid.x = 16
  float acc = 0.f;
  const int jb = seg * 256;
#pragma unroll 8
  for (int j = 0; j < 256; ++j) acc += J.v[jb + j] * J.W[(size_t)(jb + j) * 1024 + n];
  __shared__ float red[4][64];
  red[seg][cl] = acc;
  __syncthreads();
  if (seg == 0) {
    float r = red[0][cl] + red[1][cl] + red[2][cl] + red[3][cl]
            + J.s1 * J.a1[n] + (J.a2 ? J.a2[n] : 0.f);
    J.out[n] = r;
  }
}

// ---------------- LayerNorm (row = 1024) -> bf16, dual source ----------------
__global__ __launch_bounds__(256)
void ln_bf16(const float* __restrict__ in0, const float* __restrict__ g0,
             const float* __restrict__ b0, u16* __restrict__ out0,
             const float* __restrict__ in1, const float* __restrict__ g1,
             const float* __restrict__ b1, u16* __restrict__ out1, int split)
{
  int row = blockIdx.x;
  const float *in, *gw, *bw; u16* out;
  if (row < split) { in = in0; gw = g0; bw = b0; out = out0; }
  else             { in = in1; gw = g1; bw = b1; out = out1; row -= split; }
  const int t = threadIdx.x;
  const float4 v = ((const float4*)(in + (size_t)row * 1024))[t];
  float s  = v.x + v.y + v.z + v.w;
  float sq = v.x*v.x + v.y*v.y + v.z*v.z + v.w*v.w;
#pragma unroll
  for (int o = 32; o >= 1; o >>= 1) {
    s  += __shfl_xor(s, o);
    sq += __shfl_xor(sq, o);
  }
  __shared__ float red[8];
  const int wv = t >> 6;
  if ((t & 63) == 0) { red[wv] = s; red[4 + wv] = sq; }
  __syncthreads();
  s  = red[0] + red[1] + red[2] + red[3];
  sq = red[4] + red[5] + red[6] + red[7];
  const float mean = s * (1.f / 1024.f);
  const float var  = sq * (1.f / 1024.f) - mean * mean;
  const float rstd = rsqrtf(var + 1e-6f);
  const float4 g4 = ((const float4*)gw)[t];
  const float4 b4 = ((const float4*)bw)[t];
  uint2 w;
  w.x = cvtpk((v.x - mean) * rstd * g4.x + b4.x, (v.y - mean) * rstd * g4.y + b4.y);
  w.y = cvtpk((v.z - mean) * rstd * g4.z + b4.z, (v.w - mean) * rstd * g4.w + b4.w);
  ((uint2*)(out + (size_t)row * 1024))[t] = w;
}

// ---------------- segmented GEMM: C = A[M,K](bf16) @ Bt[N,K](bf16)^T ----------------
// modes: 0 bf16 row-major; 1 bf16 [B,H,L,HD]; 3 f32 (+f32 res); 4 bf16 (+bf16 res);
// 5 V-transposed (A=weight rows, Bt=activation rows), bias indexed by ROW.
struct GOut { void* ptr; const float* bias; const void* res; float oscale; int mode; };
struct Seg  { const u16* A; const u16* Bt; GOut od[2]; int odshift; int gx; int start; };
struct Segs { Seg s[8]; int total; };

template<int BM, int TPB>
__global__ __launch_bounds__(TPB)
void gemm_multi(Segs S, int K)
{
  constexpr int NW   = TPB / 64;        // waves per block
  constexpr int ROWG = NW / 2;          // row wave-groups (2 col groups)
  constexpr int WM   = BM / ROWG;       // rows per wave
  constexpr int MF   = WM / 16;         // m-fragments per wave
  constexpr int nA   = BM / 8;          // A chunks
  constexpr int PW   = (nA + 16) / NW;  // chunks per wave
  __shared__ u16 As[BM * 64];
  __shared__ u16 Bs[128 * 64];
  const int t    = threadIdx.x;
  const int lane = t & 63;
  const int wave = t >> 6;
  const int qi   = lane & 15;
  const int g    = lane >> 4;
  const int cpx  = S.total >> 3;        // XCD swizzle (total % 8 == 0)
  const int flat = blockIdx.x;
  const int nid  = (flat & 7) * cpx + (flat >> 3);
  // constant-index segment select (rule #20: no runtime-indexed aggregate)
  Seg sg = S.s[0];
#pragma unroll
  for (int k = 1; k < 8; ++k) { Seg c = S.s[k]; if (nid >= c.start) sg = c; }
  const int local = nid - sg.start;
  const int bx = local % sg.gx;
  const int by = local / sg.gx;
  const int row0 = by * BM;
  const int col0 = bx * 128;
  const int wrow = (wave >> 1) * WM;
  const int wcol = (wave & 1) * 64;

  f32x4 acc[MF][4] = {};

  const int srow  = lane >> 3;
  const int skseg = (lane & 7) * 8;
  const u16* A  = sg.A;
  const u16* Bt = sg.Bt;

  for (int kt = 0; kt < K; kt += 64) {
    __syncthreads();
#pragma unroll
    for (int i = 0; i < PW; ++i) {
      int chunk = wave * PW + i;
      if (chunk < nA) {
        GLOAD_LDS16(A + (size_t)(row0 + chunk * 8 + srow) * K + kt + skseg, As + chunk * 512);
      } else {
        int cb = chunk - nA;
        int grow = bperm(cb * 8 + srow);
        GLOAD_LDS16(Bt + (size_t)(col0 + grow) * K + kt + skseg, Bs + cb * 512);
      }
    }
    __syncthreads();
#pragma unroll
    for (int kk = 0; kk < 2; ++kk) {
      bf16x8 af[MF], bfv[4];
#pragma unroll
      for (int m = 0; m < MF; ++m)
        af[m] = *(const bf16x8*)(As + (wrow + m * 16 + qi) * 64 + kk * 32 + g * 8);
#pragma unroll
      for (int n = 0; n < 4; ++n)
        bfv[n] = *(const bf16x8*)(Bs + (wcol + n * 16 + qi) * 64 + kk * 32 + g * 8);
#pragma unroll
      for (int m = 0; m < MF; ++m)
#pragma unroll
        for (int n = 0; n < 4; ++n)
          acc[m][n] = mfma16(af[m], bfv[n], acc[m][n]);
    }
  }

  // constant-index output-descriptor select
  GOut od = sg.od[0];
  if ((bx >> sg.odshift) != 0) od = sg.od[1];
  const int cbase = (bx & ((1 << sg.odshift) - 1)) * 128 + wcol;
  const int c0 = cbase + (qi << 2);     // 4 consecutive output cols per lane
  float4 b4; b4.x = b4.y = b4.z = b4.w = 0.f;
  if (od.mode != 5 && od.bias) b4 = *(const float4*)(od.bias + c0);
#pragma unroll
  for (int m = 0; m < MF; ++m) {
#pragma unroll
    for (int j = 0; j < 4; ++j) {
      const int row = row0 + wrow + m * 16 + g * 4 + j;
      float v0 = (acc[m][0][j] + b4.x) * od.oscale;
      float v1 = (acc[m][1][j] + b4.y) * od.oscale;
      float v2 = (acc[m][2][j] + b4.z) * od.oscale;
      float v3 = (acc[m][3][j] + b4.w) * od.oscale;
      if (od.mode == 0) {
        uint2 w; w.x = cvtpk(v0, v1); w.y = cvtpk(v2, v3);
        *(uint2*)((u16*)od.ptr + (size_t)row * 1024 + c0) = w;
      } else if (od.mode == 1) {
        int bb = row >> 9, l = row & 511, hh = c0 >> 6, hd = c0 & 63;
        uint2 w; w.x = cvtpk(v0, v1); w.y = cvtpk(v2, v3);
        *(uint2*)((u16*)od.ptr + (((size_t)(bb * 16 + hh) * 512) + l) * 64 + hd) = w;
      } else if (od.mode == 5) {
        float br = od.bias[row];
        int hh = row >> 6, hd = row & 63, bb = c0 >> 9, l0 = c0 & 511;
        uint2 w; w.x = cvtpk(v0 + br, v1 + br); w.y = cvtpk(v2 + br, v3 + br);
        *(uint2*)((u16*)od.ptr + (((size_t)(bb * 16 + hh) * 64) + hd) * 512 + l0) = w;
      } else if (od.mode == 3) {
        float4 o; o.x = v0; o.y = v1; o.z = v2; o.w = v3;
        if (od.res) {
          const float4 r4 = *(const float4*)((const float*)od.res + (size_t)row * 1024 + c0);
          o.x += r4.x; o.y += r4.y; o.z += r4.z; o.w += r4.w;
        }
        *(float4*)((float*)od.ptr + (size_t)row * 1024 + c0) = o;
      } else { // 4: bf16 + bf16 res
        uint2 r = *(const uint2*)((const u16*)od.res + (size_t)row * 1024 + c0);
        uint2 w;
        w.x = cvtpk(v0 + bf2f((u16)(r.x & 0xffffu)), v1 + bf2f((u16)(r.x >> 16)));
        w.y = cvtpk(v2 + bf2f((u16)(r.y & 0xffffu)), v3 + bf2f((u16)(r.y >> 16)));
        *(uint2*)((u16*)od.ptr + (size_t)row * 1024 + c0) = w;
      }
    }
  }
}

// ---------------- quad gate GEMM (4 GEMMs + gate), BM=128/BN=64, 512 thr, 512 blocks
// gated = (sctx@WcS+bcs)*(xctx@Wx+bx) + (xctx@WcX+bcx)*(sctx@Ws+bs)
__global__ __launch_bounds__(512)
void gemm_quad_gate(const u16* __restrict__ A1, const u16* __restrict__ A2,
                    const u16* __restrict__ BWs, const u16* __restrict__ BWx,
                    const u16* __restrict__ BWcs, const u16* __restrict__ BWcx,
                    const float* __restrict__ bs, const float* __restrict__ bx,
                    const float* __restrict__ bcs, const float* __restrict__ bcx,
                    u16* __restrict__ out)
{
  __shared__ u16 As1[128 * 64];
  __shared__ u16 As2[128 * 64];
  __shared__ u16 Bs0[64 * 64];
  __shared__ u16 Bs1[64 * 64];
  __shared__ u16 Bs2[64 * 64];
  __shared__ u16 Bs3[64 * 64];
  const int t    = threadIdx.x;
  const int lane = t & 63;
  const int wave = t >> 6;                      // 0..7
  const int qi   = lane & 15;
  const int g    = lane >> 4;
  const int flat = blockIdx.x;                  // 512 blocks
  const int nid  = (flat & 7) * 64 + (flat >> 3);
  const int bxi  = nid & 15;                    // 16 col-blocks of 64
  const int byi  = nid >> 4;                    // 32 row-blocks of 128
  const int row0 = byi * 128;
  const int col0 = bxi * 64;
  const int wrow = (wave >> 1) * 32;            // 4 row groups of 32
  const int wcol = (wave & 1) * 32;             // 2 col groups of 32

  f32x4 aS1[2][2] = {}, aX1[2][2] = {}, aS2[2][2] = {}, aX2[2][2] = {};

  const int srow  = lane >> 3;
  const int skseg = (lane & 7) * 8;

  for (int kt = 0; kt < 1024; kt += 64) {
    __syncthreads();
#pragma unroll
    for (int i = 0; i < 8; ++i) {
      int chunk = wave * 8 + i;                 // 0..63
      if (chunk < 16) {
        GLOAD_LDS16(A1 + (size_t)(row0 + chunk * 8 + srow) * 1024 + kt + skseg, As1 + chunk * 512);
      } else if (chunk < 32) {
        int cb = chunk - 16;
        GLOAD_LDS16(A2 + (size_t)(row0 + cb * 8 + srow) * 1024 + kt + skseg, As2 + cb * 512);
      } else {
        int w2 = chunk - 32;
        int cb = w2 & 7;
        int grow = bperm64(cb * 8 + srow);
        const size_t goff = (size_t)(col0 + grow) * 1024 + kt + skseg;
        if (w2 < 8)       { GLOAD_LDS16(BWs  + goff, Bs0 + cb * 512); }
        else if (w2 < 16) { GLOAD_LDS16(BWx  + goff, Bs1 + cb * 512); }
        else if (w2 < 24) { GLOAD_LDS16(BWcs + goff, Bs2 + cb * 512); }
        else              { GLOAD_LDS16(BWcx + goff, Bs3 + cb * 512); }
      }
    }
    __syncthreads();
#pragma unroll
    for (int kk = 0; kk < 2; ++kk) {
      bf16x8 a1[2], a2[2], b0[2], b1[2], b2[2], b3[2];
#pragma unroll
      for (int m = 0; m < 2; ++m) {
        a1[m] = *(const bf16x8*)(As1 + (wrow + m * 16 + qi) * 64 + kk * 32 + g * 8);
        a2[m] = *(const bf16x8*)(As2 + (wrow + m * 16 + qi) * 64 + kk * 32 + g * 8);
      }
#pragma unroll
      for (int n = 0; n < 2; ++n) {
        const int ro = (wcol + n * 16 + qi) * 64 + kk * 32 + g * 8;
        b0[n] = *(const bf16x8*)(Bs0 + ro);
        b1[n] = *(const bf16x8*)(Bs1 + ro);
        b2[n] = *(const bf16x8*)(Bs2 + ro);
        b3[n] = *(const bf16x8*)(Bs3 + ro);
      }
#pragma unroll
      for (int m = 0; m < 2; ++m)
#pragma unroll
        for (int n = 0; n < 2; ++n) {
          aS1[m][n] = mfma16(a1[m], b0[n], aS1[m][n]);
          aX1[m][n] = mfma16(a2[m], b1[n], aX1[m][n]);
          aS2[m][n] = mfma16(a1[m], b2[n], aS2[m][n]);
          aX2[m][n] = mfma16(a2[m], b3[n], aX2[m][n]);
        }
    }
  }

  const int c0 = col0 + wcol + (qi << 1);       // 2 consecutive cols per lane
  const float2 vbs  = *(const float2*)(bs  + c0);
  const float2 vbx  = *(const float2*)(bx  + c0);
  const float2 vbcs = *(const float2*)(bcs + c0);
  const float2 vbcx = *(const float2*)(bcx + c0);
#pragma unroll
  for (int m = 0; m < 2; ++m) {
#pragma unroll
    for (int j = 0; j < 4; ++j) {
      const int row = row0 + wrow + m * 16 + g * 4 + j;
      float sv0 = aS1[m][0][j] + vbs.x,  sv1 = aS1[m][1][j] + vbs.y;
      float xv0 = aX1[m][0][j] + vbx.x,  xv1 = aX1[m][1][j] + vbx.y;
      float sg0 = aS2[m][0][j] + vbcs.x, sg1 = aS2[m][1][j] + vbcs.y;
      float xg0 = aX2[m][0][j] + vbcx.x, xg1 = aX2[m][1][j] + vbcx.y;
      u32 w = cvtpk(sg0 * xv0 + xg0 * sv0, sg1 * xv1 + xg1 * sv1);
      *(u32*)(out + (size_t)row * 1024 + c0) = w;
    }
  }
}

// ---------------- bilinear K=2048 (virtual concat), BM=128/BN=64, 512 thr, 512 blocks
__global__ __launch_bounds__(512)
void gemm_bilinear(const u16* __restrict__ A1, const u16* __restrict__ A2,
                   const u16* __restrict__ B1a, const u16* __restrict__ B1b,
                   const u16* __restrict__ B2a, const u16* __restrict__ B2b,
                   const float* __restrict__ bias1, const float* __restrict__ bias2,
                   const int* __restrict__ fm, u16* __restrict__ out)
{
  __shared__ u16 As[128 * 64];
  __shared__ u16 B1s[64 * 64];
  __shared__ u16 B2s[64 * 64];
  const int t    = threadIdx.x;
  const int lane = t & 63;
  const int wave = t >> 6;                      // 0..7
  const int qi   = lane & 15;
  const int g    = lane >> 4;
  const int flat = blockIdx.x;                  // 512 blocks
  const int nid  = (flat & 7) * 64 + (flat >> 3);
  const int bxi  = nid & 15;                    // 16 col-blocks of 64
  const int byi  = nid >> 4;                    // 32 row-blocks of 128
  const int row0 = byi * 128;
  const int col0 = bxi * 64;
  const int wrow = (wave >> 1) * 32;
  const int wcol = (wave & 1) * 32;

  f32x4 accS[2][2] = {};
  f32x4 accV[2][2] = {};

  const int srow  = lane >> 3;
  const int skseg = (lane & 7) * 8;

  for (int kt = 0; kt < 2048; kt += 64) {
    const u16* Ap  = (kt < 1024) ? A1  : A2;
    const u16* B1p = (kt < 1024) ? B1a : B1b;
    const u16* B2p = (kt < 1024) ? B2a : B2b;
    const int kto = kt & 1023;
    __syncthreads();
#pragma unroll
    for (int i = 0; i < 4; ++i) {
      int chunk = wave * 4 + i;                 // 0..31
      if (chunk < 16) {
        GLOAD_LDS16(Ap + (size_t)(row0 + chunk * 8 + srow) * 1024 + kto + skseg, As + chunk * 512);
      } else if (chunk < 24) {
        int cb = chunk - 16;
        int grow = bperm64(cb * 8 + srow);
        GLOAD_LDS16(B1p + (size_t)(col0 + grow) * 1024 + kto + skseg, B1s + cb * 512);
      } else {
        int cb = chunk - 24;
        int grow = bperm64(cb * 8 + srow);
        GLOAD_LDS16(B2p + (size_t)(col0 + grow) * 1024 + kto + skseg, B2s + cb * 512);
      }
    }
    __syncthreads();
#pragma unroll
    for (int kk = 0; kk < 2; ++kk) {
      bf16x8 af[2], b1[2], b2[2];
#pragma unroll
      for (int m = 0; m < 2; ++m)
        af[m] = *(const bf16x8*)(As + (wrow + m * 16 + qi) * 64 + kk * 32 + g * 8);
#pragma unroll
      for (int n = 0; n < 2; ++n) {
        const int ro = (wcol + n * 16 + qi) * 64 + kk * 32 + g * 8;
        b1[n] = *(const bf16x8*)(B1s + ro);
        b2[n] = *(const bf16x8*)(B2s + ro);
      }
#pragma unroll
      for (int m = 0; m < 2; ++m)
#pragma unroll
        for (int n = 0; n < 2; ++n) {
          accS[m][n] = mfma16(af[m], b1[n], accS[m][n]);
          accV[m][n] = mfma16(af[m], b2[n], accV[m][n]);
        }
    }
  }

  const int c0 = col0 + wcol + (qi << 1);
  const float2 b1v = *(const float2*)(bias1 + c0);
  const float2 b2v = *(const float2*)(bias2 + c0);
#pragma unroll
  for (int m = 0; m < 2; ++m) {
#pragma unroll
    for (int j = 0; j < 4; ++j) {
      const int row = row0 + wrow + m * 16 + g * 4 + j;
      const float neg = fm[row] ? 0.f : -1e30f;
      float s0 = accS[m][0][j] + b1v.x + neg;
      float s1 = accS[m][1][j] + b1v.y + neg;
      float o0 = (1.f / (1.f + expf(-s0))) * (accV[m][0][j] + b2v.x);
      float o1 = (1.f / (1.f + expf(-s1))) * (accV[m][1][j] + b2v.y);
      *(u32*)(out + (size_t)row * 1024 + c0) = cvtpk(o0, o1);
    }
  }
}

// ---------------- fused flash attention: fixed-shift softmax, 2 q-chains/wave ----
__global__ __launch_bounds__(256)
void attn_fused(const u16* __restrict__ Q,
                const u16* __restrict__ K0, const u16* __restrict__ V0,
                const u16* __restrict__ K1, const u16* __restrict__ V1,
                const int* __restrict__ qmask,
                const int* __restrict__ km0, const int* __restrict__ km1,
                u16* __restrict__ ctx0, u16* __restrict__ ctx1)
{
  const int T = 512, L = 512;
  const int lane = threadIdx.x & 63;
  const int wave = threadIdx.x >> 6;
  const int qi = lane & 15;
  const int g  = lane >> 4;
  const int bid = blockIdx.x;               // 0..1023
  const int z   = bid >> 9;
  const int ib  = bid & 511;
  const int xcd = ib & 7;
  const int iw  = ib >> 3;                  // 0..63
  const int bh  = xcd * 16 + (iw & 15);
  const int qblk = iw >> 4;                 // 0..3
  const int b  = bh >> 4;
  const int h  = bh & 15;
  const int q0a = qblk * 128 + wave * 16;
  const int q0b = q0a + 64;

  const u16* Kh = z ? K1 : K0;
  const u16* Vt = z ? V1 : V0;
  const int* kmb = (z ? km1 : km0) + b * T;
  u16* ctx = z ? ctx1 : ctx0;

  __shared__ u16 Plds[4][2][16 * 136];      // per-wave, per-chain P^T bounce
  u16* Pa = Plds[wave][0];
  u16* Pb = Plds[wave][1];

  const size_t qoffa = ((size_t)bh * L + q0a + qi) * 64;
  const size_t qoffb = ((size_t)bh * L + q0b + qi) * 64;
  const bf16x8 qa0 = *(const bf16x8*)(Q + qoffa + g * 8);
  const bf16x8 qa1 = *(const bf16x8*)(Q + qoffa + 32 + g * 8);
  const bf16x8 qb0 = *(const bf16x8*)(Q + qoffb + g * 8);
  const bf16x8 qb1 = *(const bf16x8*)(Q + qoffb + 32 + g * 8);

  const float qma = (float)qmask[b * L + q0a + qi];
  const float qmb = (float)qmask[b * L + q0b + qi];
  float tsa = 0.f, tsb = 0.f;
  f32x4 ofa[4] = {}, ofb[4] = {};

  for (int kb = 0; kb < T; kb += 128) {     // 4 iterations
    f32x4 sta[8], stb[8];
    __builtin_amdgcn_s_setprio(1);
#pragma unroll
    for (int s = 0; s < 8; ++s) {
      const size_t koff = ((size_t)bh * T + kb + s * 16 + qi) * 64;
      bf16x8 k0v = *(const bf16x8*)(Kh + koff + g * 8);
      bf16x8 k1v = *(const bf16x8*)(Kh + koff + 32 + g * 8);
      f32x4 za = {}; za = mfma16(k0v, qa0, za); sta[s] = mfma16(k1v, qa1, za);
      f32x4 zb = {}; zb = mfma16(k0v, qb0, zb); stb[s] = mfma16(k1v, qb1, zb);
    }
    __builtin_amdgcn_s_setprio(0);
#pragma unroll
    for (int s = 0; s < 8; ++s) {
      int4 km4 = *(const int4*)(kmb + kb + s * 16 + g * 4);
      const float m0 = km4.x ? 0.f : -1e30f;
      const float m1 = km4.y ? 0.f : -1e30f;
      const float m2 = km4.z ? 0.f : -1e30f;
      const float m3 = km4.w ? 0.f : -1e30f;
      float a0 = exp2f(fmaf(sta[s][0] + m0, qma, -20.f));
      float a1 = exp2f(fmaf(sta[s][1] + m1, qma, -20.f));
      float a2 = exp2f(fmaf(sta[s][2] + m2, qma, -20.f));
      float a3 = exp2f(fmaf(sta[s][3] + m3, qma, -20.f));
      tsa += (a0 + a1) + (a2 + a3);
      uint2 wa; wa.x = cvtpk(a0, a1); wa.y = cvtpk(a2, a3);
      *(uint2*)(Pa + qi * 136 + s * 16 + g * 4) = wa;
      float p0 = exp2f(fmaf(stb[s][0] + m0, qmb, -20.f));
      float p1 = exp2f(fmaf(stb[s][1] + m1, qmb, -20.f));
      float p2 = exp2f(fmaf(stb[s][2] + m2, qmb, -20.f));
      float p3 = exp2f(fmaf(stb[s][3] + m3, qmb, -20.f));
      tsb += (p0 + p1) + (p2 + p3);
      uint2 wb; wb.x = cvtpk(p0, p1); wb.y = cvtpk(p2, p3);
      *(uint2*)(Pb + qi * 136 + s * 16 + g * 4) = wb;
    }
    bf16x8 paf[4], pbf[4];
#pragma unroll
    for (int ks = 0; ks < 4; ++ks) {
      paf[ks] = *(const bf16x8*)(Pa + qi * 136 + ks * 32 + g * 8);
      pbf[ks] = *(const bf16x8*)(Pb + qi * 136 + ks * 32 + g * 8);
    }
    __builtin_amdgcn_s_setprio(1);
#pragma unroll
    for (int nf = 0; nf < 4; ++nf) {
      f32x4 oa = ofa[nf], ob = ofb[nf];
#pragma unroll
      for (int ks = 0; ks < 4; ++ks) {
        const size_t voff = ((size_t)bh * 64 + nf * 16 + qi) * (size_t)T + kb + ks * 32 + g * 8;
        bf16x8 vb = *(const bf16x8*)(Vt + voff);
        oa = mfma16(paf[ks], vb, oa);
        ob = mfma16(pbf[ks], vb, ob);
      }
      ofa[nf] = oa; ofb[nf] = ob;
    }
    __builtin_amdgcn_s_setprio(0);
  }
  tsa += __shfl_xor(tsa, 16); tsa += __shfl_xor(tsa, 32);
  tsb += __shfl_xor(tsb, 16); tsb += __shfl_xor(tsb, 32);
  const float lia = 1.f / tsa;
  const float lib = 1.f / tsb;
  float lja[4], ljb[4];
#pragma unroll
  for (int j = 0; j < 4; ++j) {
    lja[j] = __shfl(lia, g * 4 + j);
    ljb[j] = __shfl(lib, g * 4 + j);
  }
#pragma unroll
  for (int nf = 0; nf < 4; ++nf) {
    int col = h * 64 + nf * 16 + qi;
#pragma unroll
    for (int j = 0; j < 4; ++j) {
      int rowa = q0a + g * 4 + j;
      int rowb = q0b + g * 4 + j;
      ctx[((size_t)b * L + rowa) * 1024 + col] = f2bf(ofa[nf][j] * lja[j]);
      ctx[((size_t)b * L + rowb) * 1024 + col] = f2bf(ofb[nf][j] * ljb[j]);
    }
  }
}

// ---------------- driver ----------------
extern "C" void kernel_launch(void* const* d_in, const int* in_sizes, int n_in,
                              void* d_out, int out_size, void* d_ws, size_t ws_size,
                              hipStream_t stream)
{
  (void)in_sizes; (void)n_in; (void)out_size; (void)ws_size;
  const float* from = (const float*)d_in[0];
  const float* to_t = (const float*)d_in[1];
  const float* ln1g = (const float*)d_in[2];
  const float* ln1b = (const float*)d_in[3];
  const float* lntg = (const float*)d_in[4];
  const float* lntb = (const float*)d_in[5];
  const float* ln2g = (const float*)d_in[6];
  const float* ln2b = (const float*)d_in[7];
  const int* fmask = (const int*)d_in[38];
  const int* tmask = (const int*)d_in[39];

  char* ws = (char*)d_ws;
  const size_t MB = 1ull << 20;
  auto WT = [&](int i) { return (u16*)(ws + (size_t)i * 2 * MB); };   // slots 0..19 (40MB)
  // WT: 0 Wq^T 1 Wfk^T 2 Wfv^T 3 Wtk^T 4 Wtv^T 5 Ws^T 6 Wx^T 7 Wsg^T 8 Wxg^T
  //     9 Wg(plain) 10 W1^T 11 W2^T 12 Wd1^T 13 Wd2^T 14 Ws(plain) 15 Wx(plain)
  //     16 WcS^T=(Ws@Wsg)^T 17 WcX^T 18 WcG1^T=(Wg@W1)^T 19 WcG2^T
  float* bc_s   = (float*)(ws + 40 * MB);
  float* bc_x   = bc_s + 1024;
  float* bias1v = bc_s + 2048;
  float* bias2v = bc_s + 3072;
  u16*   xbf    = (u16*)(ws + 42 * MB);
  u16*   tbf    = (u16*)(ws + 50 * MB);
  u16*   qh     = (u16*)(ws + 58 * MB);
  u16*   fkh    = (u16*)(ws + 66 * MB);
  u16*   fvt    = (u16*)(ws + 74 * MB);
  u16*   tkh    = (u16*)(ws + 82 * MB);
  u16*   tvt    = (u16*)(ws + 90 * MB);
  u16*   xctx   = (u16*)(ws + 98 * MB);
  // temporally-disjoint reuse:
  u16*   sctx   = (u16*)(ws + 50 * MB);         // over tbf (dead after mega1)
  u16*   gated  = (u16*)(ws + 90 * MB);         // over tvt (dead after attn)
  u16*   abf    = (u16*)(ws + 98 * MB);         // over xctx (dead after quad)
  float* resid  = (float*)(ws + 58 * MB);       // 16MB over qh/fkh (dead after bilinear)
  u16*   lnr    = (u16*)(ws + 74 * MB);         // over fvt (dead)

  W16 wsrc;
  const int widx[14] = {8, 10, 12, 14, 16, 18, 20, 22, 24, 26, 28, 31, 34, 36};
  for (int i = 0; i < 14; ++i) wsrc.p[i] = (const float*)d_in[widx[i]];
  wsrc.p[14] = (const float*)d_in[18];   // Ws plain
  wsrc.p[15] = (const float*)d_in[20];   // Wx plain
  wconv<<<dim3(16, 16, 16), dim3(64, 4), 0, stream>>>(wsrc, (1u << 9) | (1u << 14) | (1u << 15), WT(0));

  {
    BiasJob j0{(const float*)d_in[19], (const float*)d_in[22], (const float*)d_in[23], nullptr, 1.f, bc_s};
    BiasJob j1{(const float*)d_in[21], (const float*)d_in[24], (const float*)d_in[25], nullptr, 1.f, bc_x};
    BiasJob j2{(const float*)d_in[27], (const float*)d_in[28], (const float*)d_in[29], (const float*)d_in[30], 2.f, bias1v};
    BiasJob j3{(const float*)d_in[27], (const float*)d_in[31], (const float*)d_in[32], (const float*)d_in[33], 2.f, bias2v};
    bias_comb<<<dim3(16, 4), 256, 0, stream>>>(j0, j1, j2, j3);
  }

  ln_bf16<<<8192, 256, 0, stream>>>(from, ln1g, ln1b, xbf, to_t, lntg, lntb, tbf, 4096);

  const int Kd = 1024;
  GOut z{};
  const int FAR = 0x7fffffff;

  // mega1 (BM=128): QKV projections + weight combines (1536 blocks, 6/CU)
  {
    Segs S{};
    S.s[0] = {xbf, WT(0), {{qh,  (const float*)d_in[9],  nullptr, QSCALE, 1},
                           {fkh, (const float*)d_in[11], nullptr, 1.f,    1}}, 3, 16, 0};
    S.s[1] = {tbf, WT(3), {{tkh, (const float*)d_in[15], nullptr, 1.f, 1}, z}, 3, 8, 512};
    S.s[2] = {WT(2), xbf, {{fvt, (const float*)d_in[13], nullptr, 1.f, 5}, z}, 5, 32, 768};
    S.s[3] = {WT(4), tbf, {{tvt, (const float*)d_in[17], nullptr, 1.f, 5}, z}, 5, 32, 1024};
    S.s[4] = {WT(7),  WT(14), {{WT(16), nullptr, nullptr, 1.f, 0}, z}, 3, 8, 1280};
    S.s[5] = {WT(8),  WT(15), {{WT(17), nullptr, nullptr, 1.f, 0}, z}, 3, 8, 1344};
    S.s[6] = {WT(10), WT(9),  {{WT(18), nullptr, nullptr, 1.f, 0}, z}, 3, 8, 1408};
    S.s[7] = {WT(11), WT(9),  {{WT(19), nullptr, nullptr, 1.f, 0}, z}, 3, 8, 1472};
    S.total = 1536;
    gemm_multi<128, 256><<<1536, 256, 0, stream>>>(S, Kd);
  }

  attn_fused<<<1024, 256, 0, stream>>>(qh, fkh, fvt, tkh, tvt, fmask, fmask, tmask, sctx, xctx);

  // quad gate: gated = (sctx@WcS+bc_s)*(xctx@Wx+bx) + (xctx@WcX+bc_x)*(sctx@Ws+bs)
  gemm_quad_gate<<<512, 512, 0, stream>>>(sctx, xctx, WT(5), WT(6), WT(16), WT(17),
                                          (const float*)d_in[19], (const float*)d_in[21],
                                          bc_s, bc_x, gated);

  // bilinear K=2048: scores/values from {gated, xbf}, sigmoid-gate -> abf (512 blocks)
  gemm_bilinear<<<512, 512, 0, stream>>>(gated, xbf, WT(18), WT(10), WT(19), WT(11),
                                         bias1v, bias2v, fmask, abf);

  // G_G: abf @ Wd1 + bd1 + from -> resid (f32), BM=64, 512 blocks
  {
    Segs S{};
    S.s[0] = {abf, WT(12), {{resid, (const float*)d_in[35], from, 1.f, 3}, z}, 3, 8, 0};
    S.s[1].start = FAR; S.s[2].start = FAR; S.s[3].start = FAR;
    S.s[4].start = FAR; S.s[5].start = FAR; S.s[6].start = FAR; S.s[7].start = FAR;
    S.total = 512;
    gemm_multi<64, 256><<<512, 256, 0, stream>>>(S, Kd);
  }

  ln_bf16<<<4096, 256, 0, stream>>>(resid, ln2g, ln2b, lnr, resid, ln2g, ln2b, lnr, 4096);

  // G_H: lnr @ Wd2 + bd2 + resid -> out (f32), BM=64, 512 blocks
  {
    Segs S{};
    S.s[0] = {lnr, WT(13), {{d_out, (const float*)d_in[37], resid, 1.f, 3}, z}, 3, 8, 0};
    S.s[1].start = FAR; S.s[2].start = FAR; S.s[3].start = FAR;
    S.s[4].start = FAR; S.s[5].start = FAR; S.s[6].start = FAR; S.s[7].start = FAR;
    S.total = 512;
    gemm_multi<64, 256><<<512, 256, 0, stream>>>(S, Kd);
  }
}

// Round 12
// 385.869 us; speedup vs baseline: 1.2677x; 1.0650x over previous
//
#include <hip/hip_runtime.h>

typedef unsigned short u16;
typedef unsigned int   u32;

typedef __bf16 bf16x8 __attribute__((ext_vector_type(8)));
typedef float  f32x4  __attribute__((ext_vector_type(4)));

__device__ __forceinline__ float bf2f(u16 u) {
  union { u32 i; float f; } v; v.i = ((u32)u) << 16; return v.f;
}
__device__ __forceinline__ u16 f2bf(float f) {
  union { float f; u32 i; } v; v.f = f;
  u32 r = v.i + 0x7fffu + ((v.i >> 16) & 1u);   // RNE
  return (u16)(r >> 16);
}
__device__ __forceinline__ u32 cvtpk(float a, float b) {
  u32 r;
  asm("v_cvt_pk_bf16_f32 %0, %1, %2" : "=v"(r) : "v"(a), "v"(b));
  return r;
}

__device__ __forceinline__ f32x4 mfma16(bf16x8 a, bf16x8 b, f32x4 c) {
  return __builtin_amdgcn_mfma_f32_16x16x32_bf16(a, b, c, 0, 0, 0);
}

#define GLOAD_LDS16(gsrc, ldst) \
  __builtin_amdgcn_global_load_lds((const __attribute__((address_space(1))) void*)(gsrc), \
                                   (__attribute__((address_space(3))) void*)(ldst), 16, 0, 0)

// 0.125 * log2(e): folded into Q so softmax can use exp2
#define QSCALE 0.18033688011112042f

// B-panel row permutation (128-row panels): fragment n / lane qi covers 4
// CONSECUTIVE columns qi*4+n -> packed stores.
__device__ __forceinline__ int bperm(int slot) {
  return (slot & 64) + ((slot & 15) << 2) + ((slot >> 4) & 3);
}
// 64-row variant: fragment n (0..1) / lane qi covers 2 consecutive cols qi*2+n.
__device__ __forceinline__ int bperm64(int slot) {
  return (slot & 32) + ((slot & 15) << 1) + ((slot >> 4) & 1);
}

// ---------------- weight convert: transposed (default) or plain bf16 copy ----------------
struct W16 { const float* p[16]; };

__global__ __launch_bounds__(256)
void wconv(W16 srcs, u32 plainmask, u16* __restrict__ base)
{
  __shared__ float tile[64][65];
  const int tx = threadIdx.x;           // 0..63
  const int ty = threadIdx.y;           // 0..3
  const int n0 = blockIdx.x * 64;
  const int k0 = blockIdx.y * 64;
  // constant-index select (avoid runtime-indexed kernarg aggregate -> scratch)
  const float* W = srcs.p[0];
#pragma unroll
  for (int k = 1; k < 16; ++k) if ((int)blockIdx.z == k) W = srcs.p[k];
  u16* Wt = base + ((size_t)blockIdx.z << 20);
  if ((plainmask >> blockIdx.z) & 1u) {
#pragma unroll
    for (int j = 0; j < 16; ++j) {
      int k = k0 + ty + j * 4;
      Wt[(size_t)k * 1024 + n0 + tx] = f2bf(W[(size_t)k * 1024 + n0 + tx]);
    }
    return;
  }
#pragma unroll
  for (int j = 0; j < 16; ++j) {
    int k = ty + j * 4;
    tile[k][tx] = W[(size_t)(k0 + k) * 1024 + n0 + tx];
  }
  __syncthreads();
  const int kp = tx & 31;               // k-pair index
  const int nx = (tx >> 5) * 4;         // extra n offset
#pragma unroll
  for (int j = 0; j < 8; ++j) {
    int n = ty + nx + j * 8;
    u32 w = (u32)f2bf(tile[2 * kp][n]) | ((u32)f2bf(tile[2 * kp + 1][n]) << 16);
    ((u32*)(Wt + (size_t)(n0 + n) * 1024 + k0))[kp] = w;
  }
}

// ---------------- bias combine GEMV: out[n] = v . W[:,n] + s1*a1[n] + a2[n] ----------------
struct BiasJob { const float* v; const float* W; const float* a1; const float* a2;
                 float s1; float* out; };

__global__ __launch_bounds__(256)
void bias_comb(BiasJob j0, BiasJob j1, BiasJob j2, BiasJob j3)
{
  BiasJob J = (blockIdx.y == 0) ? j0 : (blockIdx.y == 1) ? j1 : (blockIdx.y == 2) ? j2 : j3;
  const int t = threadIdx.x;
  const int cl = t & 63;
  const int seg = t >> 6;                       // 4 K-segments of 256
  const int n = blockIdx.x * 64 + cl;           // grid.x = 16
  float acc = 0.f;
  const int jb = seg * 256;
#pragma unroll 8
  for (int j = 0; j < 256; ++j) acc += J.v[jb + j] * J.W[(size_t)(jb + j) * 1024 + n];
  __shared__ float red[4][64];
  red[seg][cl] = acc;
  __syncthreads();
  if (seg == 0) {
    float r = red[0][cl] + red[1][cl] + red[2][cl] + red[3][cl]
            + J.s1 * J.a1[n] + (J.a2 ? J.a2[n] : 0.f);
    J.out[n] = r;
  }
}

// ---------------- LayerNorm (row = 1024) -> bf16, dual source ----------------
__global__ __launch_bounds__(256)
void ln_bf16(const float* __restrict__ in0, const float* __restrict__ g0,
             const float* __restrict__ b0, u16* __restrict__ out0,
             const float* __restrict__ in1, const float* __restrict__ g1,
             const float* __restrict__ b1, u16* __restrict__ out1, int split)
{
  int row = blockIdx.x;
  const float *in, *gw, *bw; u16* out;
  if (row < split) { in = in0; gw = g0; bw = b0; out = out0; }
  else             { in = in1; gw = g1; bw = b1; out = out1; row -= split; }
  const int t = threadIdx.x;
  const float4 v = ((const float4*)(in + (size_t)row * 1024))[t];
  float s  = v.x + v.y + v.z + v.w;
  float sq = v.x*v.x + v.y*v.y + v.z*v.z + v.w*v.w;
#pragma unroll
  for (int o = 32; o >= 1; o >>= 1) {
    s  += __shfl_xor(s, o);
    sq += __shfl_xor(sq, o);
  }
  __shared__ float red[8];
  const int wv = t >> 6;
  if ((t & 63) == 0) { red[wv] = s; red[4 + wv] = sq; }
  __syncthreads();
  s  = red[0] + red[1] + red[2] + red[3];
  sq = red[4] + red[5] + red[6] + red[7];
  const float mean = s * (1.f / 1024.f);
  const float var  = sq * (1.f / 1024.f) - mean * mean;
  const float rstd = rsqrtf(var + 1e-6f);
  const float4 g4 = ((const float4*)gw)[t];
  const float4 b4 = ((const float4*)bw)[t];
  uint2 w;
  w.x = cvtpk((v.x - mean) * rstd * g4.x + b4.x, (v.y - mean) * rstd * g4.y + b4.y);
  w.y = cvtpk((v.z - mean) * rstd * g4.z + b4.z, (v.w - mean) * rstd * g4.w + b4.w);
  ((uint2*)(out + (size_t)row * 1024))[t] = w;
}

// ---------------- segmented GEMM, double-buffered single-barrier K-loop -----------
// modes: 0 bf16 row-major; 1 bf16 [B,H,L,HD]; 3 f32 (+f32 res); 4 bf16 (+bf16 res);
// 5 V-transposed (A=weight rows, Bt=activation rows), bias indexed by ROW.
struct GOut { void* ptr; const float* bias; const void* res; float oscale; int mode; };
struct Seg  { const u16* A; const u16* Bt; GOut od[2]; int odshift; int gx; int start; };
struct Segs { Seg s[8]; int total; };

template<int BM, int TPB>
__global__ __launch_bounds__(TPB)
void gemm_multi(Segs S, int K)
{
  constexpr int NW   = TPB / 64;        // waves per block
  constexpr int ROWG = NW / 2;          // row wave-groups (2 col groups)
  constexpr int WM   = BM / ROWG;       // rows per wave
  constexpr int MF   = WM / 16;         // m-fragments per wave
  constexpr int nA   = BM / 8;          // A chunks
  constexpr int PW   = (nA + 16) / NW;  // chunks per wave
  __shared__ u16 As[2][BM * 64];
  __shared__ u16 Bs[2][128 * 64];
  const int t    = threadIdx.x;
  const int lane = t & 63;
  const int wave = t >> 6;
  const int qi   = lane & 15;
  const int g    = lane >> 4;
  const int cpx  = S.total >> 3;        // XCD swizzle (total % 8 == 0)
  const int flat = blockIdx.x;
  const int nid  = (flat & 7) * cpx + (flat >> 3);
  // constant-index segment select (rule #20: no runtime-indexed aggregate)
  Seg sg = S.s[0];
#pragma unroll
  for (int k = 1; k < 8; ++k) { Seg c = S.s[k]; if (nid >= c.start) sg = c; }
  const int local = nid - sg.start;
  const int bx = local % sg.gx;
  const int by = local / sg.gx;
  const int row0 = by * BM;
  const int col0 = bx * 128;
  const int wrow = (wave >> 1) * WM;
  const int wcol = (wave & 1) * 64;

  f32x4 acc[MF][4] = {};

  const int srow  = lane >> 3;
  const int skseg = (lane & 7) * 8;
  const u16* A  = sg.A;
  const u16* Bt = sg.Bt;

  // prologue: stage kt=0 into buffer 0
#pragma unroll
  for (int i = 0; i < PW; ++i) {
    int chunk = wave * PW + i;
    if (chunk < nA) {
      GLOAD_LDS16(A + (size_t)(row0 + chunk * 8 + srow) * K + skseg, As[0] + chunk * 512);
    } else {
      int cb = chunk - nA;
      int grow = bperm(cb * 8 + srow);
      GLOAD_LDS16(Bt + (size_t)(col0 + grow) * K + skseg, Bs[0] + cb * 512);
    }
  }
  __syncthreads();

  int cur = 0;
  for (int kt = 0; kt < K; kt += 64) {
    // stage NEXT K-step into the other buffer (overlaps with compute below)
    if (kt + 64 < K) {
      u16* Ad = As[cur ^ 1];
      u16* Bd = Bs[cur ^ 1];
      const int kn = kt + 64;
#pragma unroll
      for (int i = 0; i < PW; ++i) {
        int chunk = wave * PW + i;
        if (chunk < nA) {
          GLOAD_LDS16(A + (size_t)(row0 + chunk * 8 + srow) * K + kn + skseg, Ad + chunk * 512);
        } else {
          int cb = chunk - nA;
          int grow = bperm(cb * 8 + srow);
          GLOAD_LDS16(Bt + (size_t)(col0 + grow) * K + kn + skseg, Bd + cb * 512);
        }
      }
    }
    const u16* Ar = As[cur];
    const u16* Br = Bs[cur];
#pragma unroll
    for (int kk = 0; kk < 2; ++kk) {
      bf16x8 af[MF], bfv[4];
#pragma unroll
      for (int m = 0; m < MF; ++m)
        af[m] = *(const bf16x8*)(Ar + (wrow + m * 16 + qi) * 64 + kk * 32 + g * 8);
#pragma unroll
      for (int n = 0; n < 4; ++n)
        bfv[n] = *(const bf16x8*)(Br + (wcol + n * 16 + qi) * 64 + kk * 32 + g * 8);
      __builtin_amdgcn_s_setprio(1);
#pragma unroll
      for (int m = 0; m < MF; ++m)
#pragma unroll
        for (int n = 0; n < 4; ++n)
          acc[m][n] = mfma16(af[m], bfv[n], acc[m][n]);
      __builtin_amdgcn_s_setprio(0);
    }
    __syncthreads();   // drains vmcnt (stage) + lgkm; loads had full compute to land
    cur ^= 1;
  }

  // constant-index output-descriptor select
  GOut od = sg.od[0];
  if ((bx >> sg.odshift) != 0) od = sg.od[1];
  const int cbase = (bx & ((1 << sg.odshift) - 1)) * 128 + wcol;
  const int c0 = cbase + (qi << 2);     // 4 consecutive output cols per lane
  float4 b4; b4.x = b4.y = b4.z = b4.w = 0.f;
  if (od.mode != 5 && od.bias) b4 = *(const float4*)(od.bias + c0);
#pragma unroll
  for (int m = 0; m < MF; ++m) {
#pragma unroll
    for (int j = 0; j < 4; ++j) {
      const int row = row0 + wrow + m * 16 + g * 4 + j;
      float v0 = (acc[m][0][j] + b4.x) * od.oscale;
      float v1 = (acc[m][1][j] + b4.y) * od.oscale;
      float v2 = (acc[m][2][j] + b4.z) * od.oscale;
      float v3 = (acc[m][3][j] + b4.w) * od.oscale;
      if (od.mode == 0) {
        uint2 w; w.x = cvtpk(v0, v1); w.y = cvtpk(v2, v3);
        *(uint2*)((u16*)od.ptr + (size_t)row * 1024 + c0) = w;
      } else if (od.mode == 1) {
        int bb = row >> 9, l = row & 511, hh = c0 >> 6, hd = c0 & 63;
        uint2 w; w.x = cvtpk(v0, v1); w.y = cvtpk(v2, v3);
        *(uint2*)((u16*)od.ptr + (((size_t)(bb * 16 + hh) * 512) + l) * 64 + hd) = w;
      } else if (od.mode == 5) {
        float br = od.bias[row];
        int hh = row >> 6, hd = row & 63, bb = c0 >> 9, l0 = c0 & 511;
        uint2 w; w.x = cvtpk(v0 + br, v1 + br); w.y = cvtpk(v2 + br, v3 + br);
        *(uint2*)((u16*)od.ptr + (((size_t)(bb * 16 + hh) * 64) + hd) * 512 + l0) = w;
      } else if (od.mode == 3) {
        float4 o; o.x = v0; o.y = v1; o.z = v2; o.w = v3;
        if (od.res) {
          const float4 r4 = *(const float4*)((const float*)od.res + (size_t)row * 1024 + c0);
          o.x += r4.x; o.y += r4.y; o.z += r4.z; o.w += r4.w;
        }
        *(float4*)((float*)od.ptr + (size_t)row * 1024 + c0) = o;
      } else { // 4: bf16 + bf16 res
        uint2 r = *(const uint2*)((const u16*)od.res + (size_t)row * 1024 + c0);
        uint2 w;
        w.x = cvtpk(v0 + bf2f((u16)(r.x & 0xffffu)), v1 + bf2f((u16)(r.x >> 16)));
        w.y = cvtpk(v2 + bf2f((u16)(r.y & 0xffffu)), v3 + bf2f((u16)(r.y >> 16)));
        *(uint2*)((u16*)od.ptr + (size_t)row * 1024 + c0) = w;
      }
    }
  }
}

// ---------------- quad gate GEMM (4 GEMMs + gate), dbuf, BM=128/BN=64, 512 thr ----
// gated = (sctx@WcS+bcs)*(xctx@Wx+bx) + (xctx@WcX+bcx)*(sctx@Ws+bs)
__global__ __launch_bounds__(512)
void gemm_quad_gate(const u16* __restrict__ A1, const u16* __restrict__ A2,
                    const u16* __restrict__ BWs, const u16* __restrict__ BWx,
                    const u16* __restrict__ BWcs, const u16* __restrict__ BWcx,
                    const float* __restrict__ bs, const float* __restrict__ bx,
                    const float* __restrict__ bcs, const float* __restrict__ bcx,
                    u16* __restrict__ out)
{
  __shared__ u16 As1[2][128 * 64];
  __shared__ u16 As2[2][128 * 64];
  __shared__ u16 Bs0[2][64 * 64];
  __shared__ u16 Bs1[2][64 * 64];
  __shared__ u16 Bs2[2][64 * 64];
  __shared__ u16 Bs3[2][64 * 64];
  const int t    = threadIdx.x;
  const int lane = t & 63;
  const int wave = t >> 6;                      // 0..7
  const int qi   = lane & 15;
  const int g    = lane >> 4;
  const int flat = blockIdx.x;                  // 512 blocks
  const int nid  = (flat & 7) * 64 + (flat >> 3);
  const int bxi  = nid & 15;                    // 16 col-blocks of 64
  const int byi  = nid >> 4;                    // 32 row-blocks of 128
  const int row0 = byi * 128;
  const int col0 = bxi * 64;
  const int wrow = (wave >> 1) * 32;            // 4 row groups of 32
  const int wcol = (wave & 1) * 32;             // 2 col groups of 32

  f32x4 aS1[2][2] = {}, aX1[2][2] = {}, aS2[2][2] = {}, aX2[2][2] = {};

  const int srow  = lane >> 3;
  const int skseg = (lane & 7) * 8;

  // stage helper inlined twice (prologue + loop)
#define QG_STAGE(BUF, KT)                                                          \
  {                                                                                \
    _Pragma("unroll")                                                              \
    for (int i = 0; i < 8; ++i) {                                                  \
      int chunk = wave * 8 + i;                                                    \
      if (chunk < 16) {                                                            \
        GLOAD_LDS16(A1 + (size_t)(row0 + chunk * 8 + srow) * 1024 + (KT) + skseg,  \
                    As1[BUF] + chunk * 512);                                       \
      } else if (chunk < 32) {                                                     \
        int cb = chunk - 16;                                                       \
        GLOAD_LDS16(A2 + (size_t)(row0 + cb * 8 + srow) * 1024 + (KT) + skseg,     \
                    As2[BUF] + cb * 512);                                          \
      } else {                                                                     \
        int w2 = chunk - 32;                                                       \
        int cb = w2 & 7;                                                           \
        int grow = bperm64(cb * 8 + srow);                                         \
        const size_t goff = (size_t)(col0 + grow) * 1024 + (KT) + skseg;           \
        if (w2 < 8)       { GLOAD_LDS16(BWs  + goff, Bs0[BUF] + cb * 512); }       \
        else if (w2 < 16) { GLOAD_LDS16(BWx  + goff, Bs1[BUF] + cb * 512); }       \
        else if (w2 < 24) { GLOAD_LDS16(BWcs + goff, Bs2[BUF] + cb * 512); }       \
        else              { GLOAD_LDS16(BWcx + goff, Bs3[BUF] + cb * 512); }       \
      }                                                                            \
    }                                                                              \
  }

  QG_STAGE(0, 0);
  __syncthreads();

  int cur = 0;
  for (int kt = 0; kt < 1024; kt += 64) {
    if (kt + 64 < 1024) {
      if (cur == 0) { QG_STAGE(1, kt + 64); } else { QG_STAGE(0, kt + 64); }
    }
    const u16* a1p = As1[cur]; const u16* a2p = As2[cur];
    const u16* b0p = Bs0[cur]; const u16* b1p = Bs1[cur];
    const u16* b2p = Bs2[cur]; const u16* b3p = Bs3[cur];
#pragma unroll
    for (int kk = 0; kk < 2; ++kk) {
      bf16x8 a1[2], a2[2], b0[2], b1[2], b2[2], b3[2];
#pragma unroll
      for (int m = 0; m < 2; ++m) {
        a1[m] = *(const bf16x8*)(a1p + (wrow + m * 16 + qi) * 64 + kk * 32 + g * 8);
        a2[m] = *(const bf16x8*)(a2p + (wrow + m * 16 + qi) * 64 + kk * 32 + g * 8);
      }
#pragma unroll
      for (int n = 0; n < 2; ++n) {
        const int ro = (wcol + n * 16 + qi) * 64 + kk * 32 + g * 8;
        b0[n] = *(const bf16x8*)(b0p + ro);
        b1[n] = *(const bf16x8*)(b1p + ro);
        b2[n] = *(const bf16x8*)(b2p + ro);
        b3[n] = *(const bf16x8*)(b3p + ro);
      }
      __builtin_amdgcn_s_setprio(1);
#pragma unroll
      for (int m = 0; m < 2; ++m)
#pragma unroll
        for (int n = 0; n < 2; ++n) {
          aS1[m][n] = mfma16(a1[m], b0[n], aS1[m][n]);
          aX1[m][n] = mfma16(a2[m], b1[n], aX1[m][n]);
          aS2[m][n] = mfma16(a1[m], b2[n], aS2[m][n]);
          aX2[m][n] = mfma16(a2[m], b3[n], aX2[m][n]);
        }
      __builtin_amdgcn_s_setprio(0);
    }
    __syncthreads();
    cur ^= 1;
  }
#undef QG_STAGE

  const int c0 = col0 + wcol + (qi << 1);       // 2 consecutive cols per lane
  const float2 vbs  = *(const float2*)(bs  + c0);
  const float2 vbx  = *(const float2*)(bx  + c0);
  const float2 vbcs = *(const float2*)(bcs + c0);
  const float2 vbcx = *(const float2*)(bcx + c0);
#pragma unroll
  for (int m = 0; m < 2; ++m) {
#pragma unroll
    for (int j = 0; j < 4; ++j) {
      const int row = row0 + wrow + m * 16 + g * 4 + j;
      float sv0 = aS1[m][0][j] + vbs.x,  sv1 = aS1[m][1][j] + vbs.y;
      float xv0 = aX1[m][0][j] + vbx.x,  xv1 = aX1[m][1][j] + vbx.y;
      float sg0 = aS2[m][0][j] + vbcs.x, sg1 = aS2[m][1][j] + vbcs.y;
      float xg0 = aX2[m][0][j] + vbcx.x, xg1 = aX2[m][1][j] + vbcx.y;
      u32 w = cvtpk(sg0 * xv0 + xg0 * sv0, sg1 * xv1 + xg1 * sv1);
      *(u32*)(out + (size_t)row * 1024 + c0) = w;
    }
  }
}

// ---------------- bilinear K=2048 (virtual concat), dbuf, BM=128/BN=64, 512 thr ---
__global__ __launch_bounds__(512)
void gemm_bilinear(const u16* __restrict__ A1, const u16* __restrict__ A2,
                   const u16* __restrict__ B1a, const u16* __restrict__ B1b,
                   const u16* __restrict__ B2a, const u16* __restrict__ B2b,
                   const float* __restrict__ bias1, const float* __restrict__ bias2,
                   const int* __restrict__ fm, u16* __restrict__ out)
{
  __shared__ u16 As[2][128 * 64];
  __shared__ u16 B1s[2][64 * 64];
  __shared__ u16 B2s[2][64 * 64];
  const int t    = threadIdx.x;
  const int lane = t & 63;
  const int wave = t >> 6;                      // 0..7
  const int qi   = lane & 15;
  const int g    = lane >> 4;
  const int flat = blockIdx.x;                  // 512 blocks
  const int nid  = (flat & 7) * 64 + (flat >> 3);
  const int bxi  = nid & 15;                    // 16 col-blocks of 64
  const int byi  = nid >> 4;                    // 32 row-blocks of 128
  const int row0 = byi * 128;
  const int col0 = bxi * 64;
  const int wrow = (wave >> 1) * 32;
  const int wcol = (wave & 1) * 32;

  f32x4 accS[2][2] = {};
  f32x4 accV[2][2] = {};

  const int srow  = lane >> 3;
  const int skseg = (lane & 7) * 8;

#define BL_STAGE(BUF, KT)                                                          \
  {                                                                                \
    const u16* Ap  = ((KT) < 1024) ? A1  : A2;                                     \
    const u16* B1p = ((KT) < 1024) ? B1a : B1b;                                    \
    const u16* B2p = ((KT) < 1024) ? B2a : B2b;                                    \
    const int kto = (KT) & 1023;                                                   \
    _Pragma("unroll")                                                              \
    for (int i = 0; i < 4; ++i) {                                                  \
      int chunk = wave * 4 + i;                                                    \
      if (chunk < 16) {                                                            \
        GLOAD_LDS16(Ap + (size_t)(row0 + chunk * 8 + srow) * 1024 + kto + skseg,   \
                    As[BUF] + chunk * 512);                                        \
      } else if (chunk < 24) {                                                     \
        int cb = chunk - 16;                                                       \
        int grow = bperm64(cb * 8 + srow);                                         \
        GLOAD_LDS16(B1p + (size_t)(col0 + grow) * 1024 + kto + skseg,              \
                    B1s[BUF] + cb * 512);                                          \
      } else {                                                                     \
        int cb = chunk - 24;                                                       \
        int grow = bperm64(cb * 8 + srow);                                         \
        GLOAD_LDS16(B2p + (size_t)(col0 + grow) * 1024 + kto + skseg,              \
                    B2s[BUF] + cb * 512);                                          \
      }                                                                            \
    }                                                                              \
  }

  BL_STAGE(0, 0);
  __syncthreads();

  int cur = 0;
  for (int kt = 0; kt < 2048; kt += 64) {
    if (kt + 64 < 2048) {
      if (cur == 0) { BL_STAGE(1, kt + 64); } else { BL_STAGE(0, kt + 64); }
    }
    const u16* Ar  = As[cur];
    const u16* B1r = B1s[cur];
    const u16* B2r = B2s[cur];
#pragma unroll
    for (int kk = 0; kk < 2; ++kk) {
      bf16x8 af[2], b1[2], b2[2];
#pragma unroll
      for (int m = 0; m < 2; ++m)
        af[m] = *(const bf16x8*)(Ar + (wrow + m * 16 + qi) * 64 + kk * 32 + g * 8);
#pragma unroll
      for (int n = 0; n < 2; ++n) {
        const int ro = (wcol + n * 16 + qi) * 64 + kk * 32 + g * 8;
        b1[n] = *(const bf16x8*)(B1r + ro);
        b2[n] = *(const bf16x8*)(B2r + ro);
      }
      __builtin_amdgcn_s_setprio(1);
#pragma unroll
      for (int m = 0; m < 2; ++m)
#pragma unroll
        for (int n = 0; n < 2; ++n) {
          accS[m][n] = mfma16(af[m], b1[n], accS[m][n]);
          accV[m][n] = mfma16(af[m], b2[n], accV[m][n]);
        }
      __builtin_amdgcn_s_setprio(0);
    }
    __syncthreads();
    cur ^= 1;
  }
#undef BL_STAGE

  const int c0 = col0 + wcol + (qi << 1);
  const float2 b1v = *(const float2*)(bias1 + c0);
  const float2 b2v = *(const float2*)(bias2 + c0);
#pragma unroll
  for (int m = 0; m < 2; ++m) {
#pragma unroll
    for (int j = 0; j < 4; ++j) {
      const int row = row0 + wrow + m * 16 + g * 4 + j;
      const float neg = fm[row] ? 0.f : -1e30f;
      float s0 = accS[m][0][j] + b1v.x + neg;
      float s1 = accS[m][1][j] + b1v.y + neg;
      float o0 = (1.f / (1.f + expf(-s0))) * (accV[m][0][j] + b2v.x);
      float o1 = (1.f / (1.f + expf(-s1))) * (accV[m][1][j] + b2v.y);
      *(u32*)(out + (size_t)row * 1024 + c0) = cvtpk(o0, o1);
    }
  }
}

// ---------------- fused flash attention: fixed-shift softmax, 2 q-chains/wave ----
__global__ __launch_bounds__(256)
void attn_fused(const u16* __restrict__ Q,
                const u16* __restrict__ K0, const u16* __restrict__ V0,
                const u16* __restrict__ K1, const u16* __restrict__ V1,
                const int* __restrict__ qmask,
                const int* __restrict__ km0, const int* __restrict__ km1,
                u16* __restrict__ ctx0, u16* __restrict__ ctx1)
{
  const int T = 512, L = 512;
  const int lane = threadIdx.x & 63;
  const int wave = threadIdx.x >> 6;
  const int qi = lane & 15;
  const int g  = lane >> 4;
  const int bid = blockIdx.x;               // 0..1023
  const int z   = bid >> 9;
  const int ib  = bid & 511;
  const int xcd = ib & 7;
  const int iw  = ib >> 3;                  // 0..63
  const int bh  = xcd * 16 + (iw & 15);
  const int qblk = iw >> 4;                 // 0..3
  const int b  = bh >> 4;
  const int h  = bh & 15;
  const int q0a = qblk * 128 + wave * 16;
  const int q0b = q0a + 64;

  const u16* Kh = z ? K1 : K0;
  const u16* Vt = z ? V1 : V0;
  const int* kmb = (z ? km1 : km0) + b * T;
  u16* ctx = z ? ctx1 : ctx0;

  __shared__ u16 Plds[4][2][16 * 136];      // per-wave, per-chain P^T bounce
  u16* Pa = Plds[wave][0];
  u16* Pb = Plds[wave][1];

  const size_t qoffa = ((size_t)bh * L + q0a + qi) * 64;
  const size_t qoffb = ((size_t)bh * L + q0b + qi) * 64;
  const bf16x8 qa0 = *(const bf16x8*)(Q + qoffa + g * 8);
  const bf16x8 qa1 = *(const bf16x8*)(Q + qoffa + 32 + g * 8);
  const bf16x8 qb0 = *(const bf16x8*)(Q + qoffb + g * 8);
  const bf16x8 qb1 = *(const bf16x8*)(Q + qoffb + 32 + g * 8);

  const float qma = (float)qmask[b * L + q0a + qi];
  const float qmb = (float)qmask[b * L + q0b + qi];
  float tsa = 0.f, tsb = 0.f;
  f32x4 ofa[4] = {}, ofb[4] = {};

  for (int kb = 0; kb < T; kb += 128) {     // 4 iterations
    f32x4 sta[8], stb[8];
    __builtin_amdgcn_s_setprio(1);
#pragma unroll
    for (int s = 0; s < 8; ++s) {
      const size_t koff = ((size_t)bh * T + kb + s * 16 + qi) * 64;
      bf16x8 k0v = *(const bf16x8*)(Kh + koff + g * 8);
      bf16x8 k1v = *(const bf16x8*)(Kh + koff + 32 + g * 8);
      f32x4 za = {}; za = mfma16(k0v, qa0, za); sta[s] = mfma16(k1v, qa1, za);
      f32x4 zb = {}; zb = mfma16(k0v, qb0, zb); stb[s] = mfma16(k1v, qb1, zb);
    }
    __builtin_amdgcn_s_setprio(0);
#pragma unroll
    for (int s = 0; s < 8; ++s) {
      int4 km4 = *(const int4*)(kmb + kb + s * 16 + g * 4);
      const float m0 = km4.x ? 0.f : -1e30f;
      const float m1 = km4.y ? 0.f : -1e30f;
      const float m2 = km4.z ? 0.f : -1e30f;
      const float m3 = km4.w ? 0.f : -1e30f;
      float a0 = exp2f(fmaf(sta[s][0] + m0, qma, -20.f));
      float a1 = exp2f(fmaf(sta[s][1] + m1, qma, -20.f));
      float a2 = exp2f(fmaf(sta[s][2] + m2, qma, -20.f));
      float a3 = exp2f(fmaf(sta[s][3] + m3, qma, -20.f));
      tsa += (a0 + a1) + (a2 + a3);
      uint2 wa; wa.x = cvtpk(a0, a1); wa.y = cvtpk(a2, a3);
      *(uint2*)(Pa + qi * 136 + s * 16 + g * 4) = wa;
      float p0 = exp2f(fmaf(stb[s][0] + m0, qmb, -20.f));
      float p1 = exp2f(fmaf(stb[s][1] + m1, qmb, -20.f));
      float p2 = exp2f(fmaf(stb[s][2] + m2, qmb, -20.f));
      float p3 = exp2f(fmaf(stb[s][3] + m3, qmb, -20.f));
      tsb += (p0 + p1) + (p2 + p3);
      uint2 wb; wb.x = cvtpk(p0, p1); wb.y = cvtpk(p2, p3);
      *(uint2*)(Pb + qi * 136 + s * 16 + g * 4) = wb;
    }
    bf16x8 paf[4], pbf[4];
#pragma unroll
    for (int ks = 0; ks < 4; ++ks) {
      paf[ks] = *(const bf16x8*)(Pa + qi * 136 + ks * 32 + g * 8);
      pbf[ks] = *(const bf16x8*)(Pb + qi * 136 + ks * 32 + g * 8);
    }
    __builtin_amdgcn_s_setprio(1);
#pragma unroll
    for (int nf = 0; nf < 4; ++nf) {
      f32x4 oa = ofa[nf], ob = ofb[nf];
#pragma unroll
      for (int ks = 0; ks < 4; ++ks) {
        const size_t voff = ((size_t)bh * 64 + nf * 16 + qi) * (size_t)T + kb + ks * 32 + g * 8;
        bf16x8 vb = *(const bf16x8*)(Vt + voff);
        oa = mfma16(paf[ks], vb, oa);
        ob = mfma16(pbf[ks], vb, ob);
      }
      ofa[nf] = oa; ofb[nf] = ob;
    }
    __builtin_amdgcn_s_setprio(0);
  }
  tsa += __shfl_xor(tsa, 16); tsa += __shfl_xor(tsa, 32);
  tsb += __shfl_xor(tsb, 16); tsb += __shfl_xor(tsb, 32);
  const float lia = 1.f / tsa;
  const float lib = 1.f / tsb;
  float lja[4], ljb[4];
#pragma unroll
  for (int j = 0; j < 4; ++j) {
    lja[j] = __shfl(lia, g * 4 + j);
    ljb[j] = __shfl(lib, g * 4 + j);
  }
#pragma unroll
  for (int nf = 0; nf < 4; ++nf) {
    int col = h * 64 + nf * 16 + qi;
#pragma unroll
    for (int j = 0; j < 4; ++j) {
      int rowa = q0a + g * 4 + j;
      int rowb = q0b + g * 4 + j;
      ctx[((size_t)b * L + rowa) * 1024 + col] = f2bf(ofa[nf][j] * lja[j]);
      ctx[((size_t)b * L + rowb) * 1024 + col] = f2bf(ofb[nf][j] * ljb[j]);
    }
  }
}

// ---------------- driver ----------------
extern "C" void kernel_launch(void* const* d_in, const int* in_sizes, int n_in,
                              void* d_out, int out_size, void* d_ws, size_t ws_size,
                              hipStream_t stream)
{
  (void)in_sizes; (void)n_in; (void)out_size; (void)ws_size;
  const float* from = (const float*)d_in[0];
  const float* to_t = (const float*)d_in[1];
  const float* ln1g = (const float*)d_in[2];
  const float* ln1b = (const float*)d_in[3];
  const float* lntg = (const float*)d_in[4];
  const float* lntb = (const float*)d_in[5];
  const float* ln2g = (const float*)d_in[6];
  const float* ln2b = (const float*)d_in[7];
  const int* fmask = (const int*)d_in[38];
  const int* tmask = (const int*)d_in[39];

  char* ws = (char*)d_ws;
  const size_t MB = 1ull << 20;
  auto WT = [&](int i) { return (u16*)(ws + (size_t)i * 2 * MB); };   // slots 0..19 (40MB)
  // WT: 0 Wq^T 1 Wfk^T 2 Wfv^T 3 Wtk^T 4 Wtv^T 5 Ws^T 6 Wx^T 7 Wsg^T 8 Wxg^T
  //     9 Wg(plain) 10 W1^T 11 W2^T 12 Wd1^T 13 Wd2^T 14 Ws(plain) 15 Wx(plain)
  //     16 WcS^T=(Ws@Wsg)^T 17 WcX^T 18 WcG1^T=(Wg@W1)^T 19 WcG2^T
  float* bc_s   = (float*)(ws + 40 * MB);
  float* bc_x   = bc_s + 1024;
  float* bias1v = bc_s + 2048;
  float* bias2v = bc_s + 3072;
  u16*   xbf    = (u16*)(ws + 42 * MB);
  u16*   tbf    = (u16*)(ws + 50 * MB);
  u16*   qh     = (u16*)(ws + 58 * MB);
  u16*   fkh    = (u16*)(ws + 66 * MB);
  u16*   fvt    = (u16*)(ws + 74 * MB);
  u16*   tkh    = (u16*)(ws + 82 * MB);
  u16*   tvt    = (u16*)(ws + 90 * MB);
  u16*   xctx   = (u16*)(ws + 98 * MB);
  // temporally-disjoint reuse:
  u16*   sctx   = (u16*)(ws + 50 * MB);         // over tbf (dead after mega1)
  u16*   gated  = (u16*)(ws + 90 * MB);         // over tvt (dead after attn)
  u16*   abf    = (u16*)(ws + 98 * MB);         // over xctx (dead after quad)
  float* resid  = (float*)(ws + 58 * MB);       // 16MB over qh/fkh (dead after bilinear)
  u16*   lnr    = (u16*)(ws + 74 * MB);         // over fvt (dead)

  W16 wsrc;
  const int widx[14] = {8, 10, 12, 14, 16, 18, 20, 22, 24, 26, 28, 31, 34, 36};
  for (int i = 0; i < 14; ++i) wsrc.p[i] = (const float*)d_in[widx[i]];
  wsrc.p[14] = (const float*)d_in[18];   // Ws plain
  wsrc.p[15] = (const float*)d_in[20];   // Wx plain
  wconv<<<dim3(16, 16, 16), dim3(64, 4), 0, stream>>>(wsrc, (1u << 9) | (1u << 14) | (1u << 15), WT(0));

  {
    BiasJob j0{(const float*)d_in[19], (const float*)d_in[22], (const float*)d_in[23], nullptr, 1.f, bc_s};
    BiasJob j1{(const float*)d_in[21], (const float*)d_in[24], (const float*)d_in[25], nullptr, 1.f, bc_x};
    BiasJob j2{(const float*)d_in[27], (const float*)d_in[28], (const float*)d_in[29], (const float*)d_in[30], 2.f, bias1v};
    BiasJob j3{(const float*)d_in[27], (const float*)d_in[31], (const float*)d_in[32], (const float*)d_in[33], 2.f, bias2v};
    bias_comb<<<dim3(16, 4), 256, 0, stream>>>(j0, j1, j2, j3);
  }

  ln_bf16<<<8192, 256, 0, stream>>>(from, ln1g, ln1b, xbf, to_t, lntg, lntb, tbf, 4096);

  const int Kd = 1024;
  GOut z{};
  const int FAR = 0x7fffffff;

  // mega1 (BM=128, 512 thr, dbuf): QKV projections + weight combines (1536 blocks)
  {
    Segs S{};
    S.s[0] = {xbf, WT(0), {{qh,  (const float*)d_in[9],  nullptr, QSCALE, 1},
                           {fkh, (const float*)d_in[11], nullptr, 1.f,    1}}, 3, 16, 0};
    S.s[1] = {tbf, WT(3), {{tkh, (const float*)d_in[15], nullptr, 1.f, 1}, z}, 3, 8, 512};
    S.s[2] = {WT(2), xbf, {{fvt, (const float*)d_in[13], nullptr, 1.f, 5}, z}, 5, 32, 768};
    S.s[3] = {WT(4), tbf, {{tvt, (const float*)d_in[17], nullptr, 1.f, 5}, z}, 5, 32, 1024};
    S.s[4] = {WT(7),  WT(14), {{WT(16), nullptr, nullptr, 1.f, 0}, z}, 3, 8, 1280};
    S.s[5] = {WT(8),  WT(15), {{WT(17), nullptr, nullptr, 1.f, 0}, z}, 3, 8, 1344};
    S.s[6] = {WT(10), WT(9),  {{WT(18), nullptr, nullptr, 1.f, 0}, z}, 3, 8, 1408};
    S.s[7] = {WT(11), WT(9),  {{WT(19), nullptr, nullptr, 1.f, 0}, z}, 3, 8, 1472};
    S.total = 1536;
    gemm_multi<128, 512><<<1536, 512, 0, stream>>>(S, Kd);
  }

  attn_fused<<<1024, 256, 0, stream>>>(qh, fkh, fvt, tkh, tvt, fmask, fmask, tmask, sctx, xctx);

  // quad gate: gated = (sctx@WcS+bc_s)*(xctx@Wx+bx) + (xctx@WcX+bc_x)*(sctx@Ws+bs)
  gemm_quad_gate<<<512, 512, 0, stream>>>(sctx, xctx, WT(5), WT(6), WT(16), WT(17),
                                          (const float*)d_in[19], (const float*)d_in[21],
                                          bc_s, bc_x, gated);

  // bilinear K=2048: scores/values from {gated, xbf}, sigmoid-gate -> abf (512 blocks)
  gemm_bilinear<<<512, 512, 0, stream>>>(gated, xbf, WT(18), WT(10), WT(19), WT(11),
                                         bias1v, bias2v, fmask, abf);

  // G_G: abf @ Wd1 + bd1 + from -> resid (f32), BM=64, 512 blocks
  {
    Segs S{};
    S.s[0] = {abf, WT(12), {{resid, (const float*)d_in[35], from, 1.f, 3}, z}, 3, 8, 0};
    S.s[1].start = FAR; S.s[2].start = FAR; S.s[3].start = FAR;
    S.s[4].start = FAR; S.s[5].start = FAR; S.s[6].start = FAR; S.s[7].start = FAR;
    S.total = 512;
    gemm_multi<64, 256><<<512, 256, 0, stream>>>(S, Kd);
  }

  ln_bf16<<<4096, 256, 0, stream>>>(resid, ln2g, ln2b, lnr, resid, ln2g, ln2b, lnr, 4096);

  // G_H: lnr @ Wd2 + bd2 + resid -> out (f32), BM=64, 512 blocks
  {
    Segs S{};
    S.s[0] = {lnr, WT(13), {{d_out, (const float*)d_in[37], resid, 1.f, 3}, z}, 3, 8, 0};
    S.s[1].start = FAR; S.s[2].start = FAR; S.s[3].start = FAR;
    S.s[4].start = FAR; S.s[5].start = FAR; S.s[6].start = FAR; S.s[7].start = FAR;
    S.total = 512;
    gemm_multi<64, 256><<<512, 256, 0, stream>>>(S, Kd);
  }
}

// Round 13
// 329.965 us; speedup vs baseline: 1.4824x; 1.1694x over previous
//
#include <hip/hip_runtime.h>

typedef unsigned short u16;
typedef unsigned int   u32;

typedef __bf16 bf16x8 __attribute__((ext_vector_type(8)));
typedef float  f32x4  __attribute__((ext_vector_type(4)));

__device__ __forceinline__ float bf2f(u16 u) {
  union { u32 i; float f; } v; v.i = ((u32)u) << 16; return v.f;
}
__device__ __forceinline__ u16 f2bf(float f) {
  union { float f; u32 i; } v; v.f = f;
  u32 r = v.i + 0x7fffu + ((v.i >> 16) & 1u);   // RNE
  return (u16)(r >> 16);
}
__device__ __forceinline__ u32 cvtpk(float a, float b) {
  u32 r;
  asm("v_cvt_pk_bf16_f32 %0, %1, %2" : "=v"(r) : "v"(a), "v"(b));
  return r;
}

__device__ __forceinline__ f32x4 mfma16(bf16x8 a, bf16x8 b, f32x4 c) {
  return __builtin_amdgcn_mfma_f32_16x16x32_bf16(a, b, c, 0, 0, 0);
}

#define GLOAD_LDS16(gsrc, ldst) \
  __builtin_amdgcn_global_load_lds((const __attribute__((address_space(1))) void*)(gsrc), \
                                   (__attribute__((address_space(3))) void*)(ldst), 16, 0, 0)

// 0.125 * log2(e): folded into Q so softmax can use exp2
#define QSCALE 0.18033688011112042f

// LDS k-swizzle (T2, gload_lds-legal): LDS(row, p) holds global k = p ^ ((row&7)*8).
// Stage: lane's global k-offset = ((lane&7) ^ srow)*8  (coalescing preserved).
// Read:  k-offset = (kk*32 + g*8) ^ ((qi&7)*8)  (row&7 == qi&7 for all fragment rows).
// Spreads each quarter-wave's ds_read_b128 across 8 16B-columns -> 2-way (free).

// B-panel row permutation (128-row panels): fragment n / lane qi covers 4
// CONSECUTIVE columns qi*4+n -> packed stores.
__device__ __forceinline__ int bperm(int slot) {
  return (slot & 64) + ((slot & 15) << 2) + ((slot >> 4) & 3);
}
// 64-row variant: fragment n (0..1) / lane qi covers 2 consecutive cols qi*2+n.
__device__ __forceinline__ int bperm64(int slot) {
  return (slot & 32) + ((slot & 15) << 1) + ((slot >> 4) & 1);
}

// ---------------- weight convert: transposed (default) or plain bf16 copy ----------------
struct W16 { const float* p[16]; };

__global__ __launch_bounds__(256)
void wconv(W16 srcs, u32 plainmask, u16* __restrict__ base)
{
  __shared__ float tile[64][65];
  const int tx = threadIdx.x;           // 0..63
  const int ty = threadIdx.y;           // 0..3
  const int n0 = blockIdx.x * 64;
  const int k0 = blockIdx.y * 64;
  // constant-index select (avoid runtime-indexed kernarg aggregate -> scratch)
  const float* W = srcs.p[0];
#pragma unroll
  for (int k = 1; k < 16; ++k) if ((int)blockIdx.z == k) W = srcs.p[k];
  u16* Wt = base + ((size_t)blockIdx.z << 20);
  if ((plainmask >> blockIdx.z) & 1u) {
#pragma unroll
    for (int j = 0; j < 16; ++j) {
      int k = k0 + ty + j * 4;
      Wt[(size_t)k * 1024 + n0 + tx] = f2bf(W[(size_t)k * 1024 + n0 + tx]);
    }
    return;
  }
#pragma unroll
  for (int j = 0; j < 16; ++j) {
    int k = ty + j * 4;
    tile[k][tx] = W[(size_t)(k0 + k) * 1024 + n0 + tx];
  }
  __syncthreads();
  const int kp = tx & 31;               // k-pair index
  const int nx = (tx >> 5) * 4;         // extra n offset
#pragma unroll
  for (int j = 0; j < 8; ++j) {
    int n = ty + nx + j * 8;
    u32 w = (u32)f2bf(tile[2 * kp][n]) | ((u32)f2bf(tile[2 * kp + 1][n]) << 16);
    ((u32*)(Wt + (size_t)(n0 + n) * 1024 + k0))[kp] = w;
  }
}

// ---------------- bias combine GEMV: out[n] = v . W[:,n] + s1*a1[n] + a2[n] ----------------
struct BiasJob { const float* v; const float* W; const float* a1; const float* a2;
                 float s1; float* out; };

__global__ __launch_bounds__(256)
void bias_comb(BiasJob j0, BiasJob j1, BiasJob j2, BiasJob j3)
{
  BiasJob J = (blockIdx.y == 0) ? j0 : (blockIdx.y == 1) ? j1 : (blockIdx.y == 2) ? j2 : j3;
  const int t = threadIdx.x;
  const int cl = t & 63;
  const int seg = t >> 6;                       // 4 K-segments of 256
  const int n = blockIdx.x * 64 + cl;           // grid.x = 16
  float acc = 0.f;
  const int jb = seg * 256;
#pragma unroll 8
  for (int j = 0; j < 256; ++j) acc += J.v[jb + j] * J.W[(size_t)(jb + j) * 1024 + n];
  __shared__ float red[4][64];
  red[seg][cl] = acc;
  __syncthreads();
  if (seg == 0) {
    float r = red[0][cl] + red[1][cl] + red[2][cl] + red[3][cl]
            + J.s1 * J.a1[n] + (J.a2 ? J.a2[n] : 0.f);
    J.out[n] = r;
  }
}

// ---------------- LayerNorm (row = 1024) -> bf16, dual source ----------------
__global__ __launch_bounds__(256)
void ln_bf16(const float* __restrict__ in0, const float* __restrict__ g0,
             const float* __restrict__ b0, u16* __restrict__ out0,
             const float* __restrict__ in1, const float* __restrict__ g1,
             const float* __restrict__ b1, u16* __restrict__ out1, int split)
{
  int row = blockIdx.x;
  const float *in, *gw, *bw; u16* out;
  if (row < split) { in = in0; gw = g0; bw = b0; out = out0; }
  else             { in = in1; gw = g1; bw = b1; out = out1; row -= split; }
  const int t = threadIdx.x;
  const float4 v = ((const float4*)(in + (size_t)row * 1024))[t];
  float s  = v.x + v.y + v.z + v.w;
  float sq = v.x*v.x + v.y*v.y + v.z*v.z + v.w*v.w;
#pragma unroll
  for (int o = 32; o >= 1; o >>= 1) {
    s  += __shfl_xor(s, o);
    sq += __shfl_xor(sq, o);
  }
  __shared__ float red[8];
  const int wv = t >> 6;
  if ((t & 63) == 0) { red[wv] = s; red[4 + wv] = sq; }
  __syncthreads();
  s  = red[0] + red[1] + red[2] + red[3];
  sq = red[4] + red[5] + red[6] + red[7];
  const float mean = s * (1.f / 1024.f);
  const float var  = sq * (1.f / 1024.f) - mean * mean;
  const float rstd = rsqrtf(var + 1e-6f);
  const float4 g4 = ((const float4*)gw)[t];
  const float4 b4 = ((const float4*)bw)[t];
  uint2 w;
  w.x = cvtpk((v.x - mean) * rstd * g4.x + b4.x, (v.y - mean) * rstd * g4.y + b4.y);
  w.y = cvtpk((v.z - mean) * rstd * g4.z + b4.z, (v.w - mean) * rstd * g4.w + b4.w);
  ((uint2*)(out + (size_t)row * 1024))[t] = w;
}

// ---------------- segmented GEMM, dbuf single-barrier K-loop, swizzled LDS --------
// modes: 0 bf16 row-major; 1 bf16 [B,H,L,HD]; 3 f32 (+f32 res); 4 bf16 (+bf16 res);
// 5 V-transposed (A=weight rows, Bt=activation rows), bias indexed by ROW.
struct GOut { void* ptr; const float* bias; const void* res; float oscale; int mode; };
struct Seg  { const u16* A; const u16* Bt; GOut od[2]; int odshift; int gx; int start; };
struct Segs { Seg s[8]; int total; };

template<int BM, int TPB>
__global__ __launch_bounds__(TPB)
void gemm_multi(Segs S, int K)
{
  constexpr int NW   = TPB / 64;        // waves per block
  constexpr int ROWG = NW / 2;          // row wave-groups (2 col groups)
  constexpr int WM   = BM / ROWG;       // rows per wave
  constexpr int MF   = WM / 16;         // m-fragments per wave
  constexpr int nA   = BM / 8;          // A chunks
  constexpr int PW   = (nA + 16) / NW;  // chunks per wave
  __shared__ u16 As[2][BM * 64];
  __shared__ u16 Bs[2][128 * 64];
  const int t    = threadIdx.x;
  const int lane = t & 63;
  const int wave = t >> 6;
  const int qi   = lane & 15;
  const int g    = lane >> 4;
  const int cpx  = S.total >> 3;        // XCD swizzle (total % 8 == 0)
  const int flat = blockIdx.x;
  const int nid  = (flat & 7) * cpx + (flat >> 3);
  // constant-index segment select (rule #20: no runtime-indexed aggregate)
  Seg sg = S.s[0];
#pragma unroll
  for (int k = 1; k < 8; ++k) { Seg c = S.s[k]; if (nid >= c.start) sg = c; }
  const int local = nid - sg.start;
  const int bx = local % sg.gx;
  const int by = local / sg.gx;
  const int row0 = by * BM;
  const int col0 = bx * 128;
  const int wrow = (wave >> 1) * WM;
  const int wcol = (wave & 1) * 64;

  f32x4 acc[MF][4] = {};

  const int srow  = lane >> 3;
  const int skseg = (((lane & 7) ^ srow) * 8);   // swizzled global k-offset
  const int rsw   = (qi & 7) * 8;                // read-side XOR key
  const u16* A  = sg.A;
  const u16* Bt = sg.Bt;

  // prologue: stage kt=0 into buffer 0
#pragma unroll
  for (int i = 0; i < PW; ++i) {
    int chunk = wave * PW + i;
    if (chunk < nA) {
      GLOAD_LDS16(A + (size_t)(row0 + chunk * 8 + srow) * K + skseg, As[0] + chunk * 512);
    } else {
      int cb = chunk - nA;
      int grow = bperm(cb * 8 + srow);
      GLOAD_LDS16(Bt + (size_t)(col0 + grow) * K + skseg, Bs[0] + cb * 512);
    }
  }
  __syncthreads();

  int cur = 0;
  for (int kt = 0; kt < K; kt += 64) {
    // stage NEXT K-step into the other buffer (overlaps with compute below)
    if (kt + 64 < K) {
      u16* Ad = As[cur ^ 1];
      u16* Bd = Bs[cur ^ 1];
      const int kn = kt + 64;
#pragma unroll
      for (int i = 0; i < PW; ++i) {
        int chunk = wave * PW + i;
        if (chunk < nA) {
          GLOAD_LDS16(A + (size_t)(row0 + chunk * 8 + srow) * K + kn + skseg, Ad + chunk * 512);
        } else {
          int cb = chunk - nA;
          int grow = bperm(cb * 8 + srow);
          GLOAD_LDS16(Bt + (size_t)(col0 + grow) * K + kn + skseg, Bd + cb * 512);
        }
      }
    }
    const u16* Ar = As[cur];
    const u16* Br = Bs[cur];
#pragma unroll
    for (int kk = 0; kk < 2; ++kk) {
      const int ko = (kk * 32 + g * 8) ^ rsw;
      bf16x8 af[MF], bfv[4];
#pragma unroll
      for (int m = 0; m < MF; ++m)
        af[m] = *(const bf16x8*)(Ar + (wrow + m * 16 + qi) * 64 + ko);
#pragma unroll
      for (int n = 0; n < 4; ++n)
        bfv[n] = *(const bf16x8*)(Br + (wcol + n * 16 + qi) * 64 + ko);
      __builtin_amdgcn_s_setprio(1);
#pragma unroll
      for (int m = 0; m < MF; ++m)
#pragma unroll
        for (int n = 0; n < 4; ++n)
          acc[m][n] = mfma16(af[m], bfv[n], acc[m][n]);
      __builtin_amdgcn_s_setprio(0);
    }
    __syncthreads();   // drains vmcnt (stage) + lgkm; loads had full compute to land
    cur ^= 1;
  }

  // constant-index output-descriptor select
  GOut od = sg.od[0];
  if ((bx >> sg.odshift) != 0) od = sg.od[1];
  const int cbase = (bx & ((1 << sg.odshift) - 1)) * 128 + wcol;
  const int c0 = cbase + (qi << 2);     // 4 consecutive output cols per lane
  float4 b4; b4.x = b4.y = b4.z = b4.w = 0.f;
  if (od.mode != 5 && od.bias) b4 = *(const float4*)(od.bias + c0);
#pragma unroll
  for (int m = 0; m < MF; ++m) {
#pragma unroll
    for (int j = 0; j < 4; ++j) {
      const int row = row0 + wrow + m * 16 + g * 4 + j;
      float v0 = (acc[m][0][j] + b4.x) * od.oscale;
      float v1 = (acc[m][1][j] + b4.y) * od.oscale;
      float v2 = (acc[m][2][j] + b4.z) * od.oscale;
      float v3 = (acc[m][3][j] + b4.w) * od.oscale;
      if (od.mode == 0) {
        uint2 w; w.x = cvtpk(v0, v1); w.y = cvtpk(v2, v3);
        *(uint2*)((u16*)od.ptr + (size_t)row * 1024 + c0) = w;
      } else if (od.mode == 1) {
        int bb = row >> 9, l = row & 511, hh = c0 >> 6, hd = c0 & 63;
        uint2 w; w.x = cvtpk(v0, v1); w.y = cvtpk(v2, v3);
        *(uint2*)((u16*)od.ptr + (((size_t)(bb * 16 + hh) * 512) + l) * 64 + hd) = w;
      } else if (od.mode == 5) {
        float br = od.bias[row];
        int hh = row >> 6, hd = row & 63, bb = c0 >> 9, l0 = c0 & 511;
        uint2 w; w.x = cvtpk(v0 + br, v1 + br); w.y = cvtpk(v2 + br, v3 + br);
        *(uint2*)((u16*)od.ptr + (((size_t)(bb * 16 + hh) * 64) + hd) * 512 + l0) = w;
      } else if (od.mode == 3) {
        float4 o; o.x = v0; o.y = v1; o.z = v2; o.w = v3;
        if (od.res) {
          const float4 r4 = *(const float4*)((const float*)od.res + (size_t)row * 1024 + c0);
          o.x += r4.x; o.y += r4.y; o.z += r4.z; o.w += r4.w;
        }
        *(float4*)((float*)od.ptr + (size_t)row * 1024 + c0) = o;
      } else { // 4: bf16 + bf16 res
        uint2 r = *(const uint2*)((const u16*)od.res + (size_t)row * 1024 + c0);
        uint2 w;
        w.x = cvtpk(v0 + bf2f((u16)(r.x & 0xffffu)), v1 + bf2f((u16)(r.x >> 16)));
        w.y = cvtpk(v2 + bf2f((u16)(r.y & 0xffffu)), v3 + bf2f((u16)(r.y >> 16)));
        *(uint2*)((u16*)od.ptr + (size_t)row * 1024 + c0) = w;
      }
    }
  }
}

// ---------------- quad gate GEMM (4 GEMMs + gate), dbuf, swizzled, BM=128/BN=64 ---
// gated = (sctx@WcS+bcs)*(xctx@Wx+bx) + (xctx@WcX+bcx)*(sctx@Ws+bs)
__global__ __launch_bounds__(512)
void gemm_quad_gate(const u16* __restrict__ A1, const u16* __restrict__ A2,
                    const u16* __restrict__ BWs, const u16* __restrict__ BWx,
                    const u16* __restrict__ BWcs, const u16* __restrict__ BWcx,
                    const float* __restrict__ bs, const float* __restrict__ bx,
                    const float* __restrict__ bcs, const float* __restrict__ bcx,
                    u16* __restrict__ out)
{
  __shared__ u16 As1[2][128 * 64];
  __shared__ u16 As2[2][128 * 64];
  __shared__ u16 Bs0[2][64 * 64];
  __shared__ u16 Bs1[2][64 * 64];
  __shared__ u16 Bs2[2][64 * 64];
  __shared__ u16 Bs3[2][64 * 64];
  const int t    = threadIdx.x;
  const int lane = t & 63;
  const int wave = t >> 6;                      // 0..7
  const int qi   = lane & 15;
  const int g    = lane >> 4;
  const int flat = blockIdx.x;                  // 512 blocks
  const int nid  = (flat & 7) * 64 + (flat >> 3);
  const int bxi  = nid & 15;                    // 16 col-blocks of 64
  const int byi  = nid >> 4;                    // 32 row-blocks of 128
  const int row0 = byi * 128;
  const int col0 = bxi * 64;
  const int wrow = (wave >> 1) * 32;            // 4 row groups of 32
  const int wcol = (wave & 1) * 32;             // 2 col groups of 32

  f32x4 aS1[2][2] = {}, aX1[2][2] = {}, aS2[2][2] = {}, aX2[2][2] = {};

  const int srow  = lane >> 3;
  const int skseg = (((lane & 7) ^ srow) * 8);
  const int rsw   = (qi & 7) * 8;

#define QG_STAGE(BUF, KT)                                                          \
  {                                                                                \
    _Pragma("unroll")                                                              \
    for (int i = 0; i < 8; ++i) {                                                  \
      int chunk = wave * 8 + i;                                                    \
      if (chunk < 16) {                                                            \
        GLOAD_LDS16(A1 + (size_t)(row0 + chunk * 8 + srow) * 1024 + (KT) + skseg,  \
                    As1[BUF] + chunk * 512);                                       \
      } else if (chunk < 32) {                                                     \
        int cb = chunk - 16;                                                       \
        GLOAD_LDS16(A2 + (size_t)(row0 + cb * 8 + srow) * 1024 + (KT) + skseg,     \
                    As2[BUF] + cb * 512);                                          \
      } else {                                                                     \
        int w2 = chunk - 32;                                                       \
        int cb = w2 & 7;                                                           \
        int grow = bperm64(cb * 8 + srow);                                         \
        const size_t goff = (size_t)(col0 + grow) * 1024 + (KT) + skseg;           \
        if (w2 < 8)       { GLOAD_LDS16(BWs  + goff, Bs0[BUF] + cb * 512); }       \
        else if (w2 < 16) { GLOAD_LDS16(BWx  + goff, Bs1[BUF] + cb * 512); }       \
        else if (w2 < 24) { GLOAD_LDS16(BWcs + goff, Bs2[BUF] + cb * 512); }       \
        else              { GLOAD_LDS16(BWcx + goff, Bs3[BUF] + cb * 512); }       \
      }                                                                            \
    }                                                                              \
  }

  QG_STAGE(0, 0);
  __syncthreads();

  int cur = 0;
  for (int kt = 0; kt < 1024; kt += 64) {
    if (kt + 64 < 1024) {
      if (cur == 0) { QG_STAGE(1, kt + 64); } else { QG_STAGE(0, kt + 64); }
    }
    const u16* a1p = As1[cur]; const u16* a2p = As2[cur];
    const u16* b0p = Bs0[cur]; const u16* b1p = Bs1[cur];
    const u16* b2p = Bs2[cur]; const u16* b3p = Bs3[cur];
#pragma unroll
    for (int kk = 0; kk < 2; ++kk) {
      const int ko = (kk * 32 + g * 8) ^ rsw;
      bf16x8 a1[2], a2[2], b0[2], b1[2], b2[2], b3[2];
#pragma unroll
      for (int m = 0; m < 2; ++m) {
        a1[m] = *(const bf16x8*)(a1p + (wrow + m * 16 + qi) * 64 + ko);
        a2[m] = *(const bf16x8*)(a2p + (wrow + m * 16 + qi) * 64 + ko);
      }
#pragma unroll
      for (int n = 0; n < 2; ++n) {
        const int ro = (wcol + n * 16 + qi) * 64 + ko;
        b0[n] = *(const bf16x8*)(b0p + ro);
        b1[n] = *(const bf16x8*)(b1p + ro);
        b2[n] = *(const bf16x8*)(b2p + ro);
        b3[n] = *(const bf16x8*)(b3p + ro);
      }
      __builtin_amdgcn_s_setprio(1);
#pragma unroll
      for (int m = 0; m < 2; ++m)
#pragma unroll
        for (int n = 0; n < 2; ++n) {
          aS1[m][n] = mfma16(a1[m], b0[n], aS1[m][n]);
          aX1[m][n] = mfma16(a2[m], b1[n], aX1[m][n]);
          aS2[m][n] = mfma16(a1[m], b2[n], aS2[m][n]);
          aX2[m][n] = mfma16(a2[m], b3[n], aX2[m][n]);
        }
      __builtin_amdgcn_s_setprio(0);
    }
    __syncthreads();
    cur ^= 1;
  }
#undef QG_STAGE

  const int c0 = col0 + wcol + (qi << 1);       // 2 consecutive cols per lane
  const float2 vbs  = *(const float2*)(bs  + c0);
  const float2 vbx  = *(const float2*)(bx  + c0);
  const float2 vbcs = *(const float2*)(bcs + c0);
  const float2 vbcx = *(const float2*)(bcx + c0);
#pragma unroll
  for (int m = 0; m < 2; ++m) {
#pragma unroll
    for (int j = 0; j < 4; ++j) {
      const int row = row0 + wrow + m * 16 + g * 4 + j;
      float sv0 = aS1[m][0][j] + vbs.x,  sv1 = aS1[m][1][j] + vbs.y;
      float xv0 = aX1[m][0][j] + vbx.x,  xv1 = aX1[m][1][j] + vbx.y;
      float sg0 = aS2[m][0][j] + vbcs.x, sg1 = aS2[m][1][j] + vbcs.y;
      float xg0 = aX2[m][0][j] + vbcx.x, xg1 = aX2[m][1][j] + vbcx.y;
      u32 w = cvtpk(sg0 * xv0 + xg0 * sv0, sg1 * xv1 + xg1 * sv1);
      *(u32*)(out + (size_t)row * 1024 + c0) = w;
    }
  }
}

// ---------------- bilinear K=2048 (virtual concat), dbuf, swizzled, BM=128/BN=64 --
__global__ __launch_bounds__(512)
void gemm_bilinear(const u16* __restrict__ A1, const u16* __restrict__ A2,
                   const u16* __restrict__ B1a, const u16* __restrict__ B1b,
                   const u16* __restrict__ B2a, const u16* __restrict__ B2b,
                   const float* __restrict__ bias1, const float* __restrict__ bias2,
                   const int* __restrict__ fm, u16* __restrict__ out)
{
  __shared__ u16 As[2][128 * 64];
  __shared__ u16 B1s[2][64 * 64];
  __shared__ u16 B2s[2][64 * 64];
  const int t    = threadIdx.x;
  const int lane = t & 63;
  const int wave = t >> 6;                      // 0..7
  const int qi   = lane & 15;
  const int g    = lane >> 4;
  const int flat = blockIdx.x;                  // 512 blocks
  const int nid  = (flat & 7) * 64 + (flat >> 3);
  const int bxi  = nid & 15;                    // 16 col-blocks of 64
  const int byi  = nid >> 4;                    // 32 row-blocks of 128
  const int row0 = byi * 128;
  const int col0 = bxi * 64;
  const int wrow = (wave >> 1) * 32;
  const int wcol = (wave & 1) * 32;

  f32x4 accS[2][2] = {};
  f32x4 accV[2][2] = {};

  const int srow  = lane >> 3;
  const int skseg = (((lane & 7) ^ srow) * 8);
  const int rsw   = (qi & 7) * 8;

#define BL_STAGE(BUF, KT)                                                          \
  {                                                                                \
    const u16* Ap  = ((KT) < 1024) ? A1  : A2;                                     \
    const u16* B1p = ((KT) < 1024) ? B1a : B1b;                                    \
    const u16* B2p = ((KT) < 1024) ? B2a : B2b;                                    \
    const int kto = (KT) & 1023;                                                   \
    _Pragma("unroll")                                                              \
    for (int i = 0; i < 4; ++i) {                                                  \
      int chunk = wave * 4 + i;                                                    \
      if (chunk < 16) {                                                            \
        GLOAD_LDS16(Ap + (size_t)(row0 + chunk * 8 + srow) * 1024 + kto + skseg,   \
                    As[BUF] + chunk * 512);                                        \
      } else if (chunk < 24) {                                                     \
        int cb = chunk - 16;                                                       \
        int grow = bperm64(cb * 8 + srow);                                         \
        GLOAD_LDS16(B1p + (size_t)(col0 + grow) * 1024 + kto + skseg,              \
                    B1s[BUF] + cb * 512);                                          \
      } else {                                                                     \
        int cb = chunk - 24;                                                       \
        int grow = bperm64(cb * 8 + srow);                                         \
        GLOAD_LDS16(B2p + (size_t)(col0 + grow) * 1024 + kto + skseg,              \
                    B2s[BUF] + cb * 512);                                          \
      }                                                                            \
    }                                                                              \
  }

  BL_STAGE(0, 0);
  __syncthreads();

  int cur = 0;
  for (int kt = 0; kt < 2048; kt += 64) {
    if (kt + 64 < 2048) {
      if (cur == 0) { BL_STAGE(1, kt + 64); } else { BL_STAGE(0, kt + 64); }
    }
    const u16* Ar  = As[cur];
    const u16* B1r = B1s[cur];
    const u16* B2r = B2s[cur];
#pragma unroll
    for (int kk = 0; kk < 2; ++kk) {
      const int ko = (kk * 32 + g * 8) ^ rsw;
      bf16x8 af[2], b1[2], b2[2];
#pragma unroll
      for (int m = 0; m < 2; ++m)
        af[m] = *(const bf16x8*)(Ar + (wrow + m * 16 + qi) * 64 + ko);
#pragma unroll
      for (int n = 0; n < 2; ++n) {
        const int ro = (wcol + n * 16 + qi) * 64 + ko;
        b1[n] = *(const bf16x8*)(B1r + ro);
        b2[n] = *(const bf16x8*)(B2r + ro);
      }
      __builtin_amdgcn_s_setprio(1);
#pragma unroll
      for (int m = 0; m < 2; ++m)
#pragma unroll
        for (int n = 0; n < 2; ++n) {
          accS[m][n] = mfma16(af[m], b1[n], accS[m][n]);
          accV[m][n] = mfma16(af[m], b2[n], accV[m][n]);
        }
      __builtin_amdgcn_s_setprio(0);
    }
    __syncthreads();
    cur ^= 1;
  }
#undef BL_STAGE

  const int c0 = col0 + wcol + (qi << 1);
  const float2 b1v = *(const float2*)(bias1 + c0);
  const float2 b2v = *(const float2*)(bias2 + c0);
#pragma unroll
  for (int m = 0; m < 2; ++m) {
#pragma unroll
    for (int j = 0; j < 4; ++j) {
      const int row = row0 + wrow + m * 16 + g * 4 + j;
      const float neg = fm[row] ? 0.f : -1e30f;
      float s0 = accS[m][0][j] + b1v.x + neg;
      float s1 = accS[m][1][j] + b1v.y + neg;
      float o0 = (1.f / (1.f + expf(-s0))) * (accV[m][0][j] + b2v.x);
      float o1 = (1.f / (1.f + expf(-s1))) * (accV[m][1][j] + b2v.y);
      *(u32*)(out + (size_t)row * 1024 + c0) = cvtpk(o0, o1);
    }
  }
}

// ---------------- fused flash attention: fixed-shift softmax, 2 q-chains/wave ----
__global__ __launch_bounds__(256)
void attn_fused(const u16* __restrict__ Q,
                const u16* __restrict__ K0, const u16* __restrict__ V0,
                const u16* __restrict__ K1, const u16* __restrict__ V1,
                const int* __restrict__ qmask,
                const int* __restrict__ km0, const int* __restrict__ km1,
                u16* __restrict__ ctx0, u16* __restrict__ ctx1)
{
  const int T = 512, L = 512;
  const int lane = threadIdx.x & 63;
  const int wave = threadIdx.x >> 6;
  const int qi = lane & 15;
  const int g  = lane >> 4;
  const int bid = blockIdx.x;               // 0..1023
  const int z   = bid >> 9;
  const int ib  = bid & 511;
  const int xcd = ib & 7;
  const int iw  = ib >> 3;                  // 0..63
  const int bh  = xcd * 16 + (iw & 15);
  const int qblk = iw >> 4;                 // 0..3
  const int b  = bh >> 4;
  const int h  = bh & 15;
  const int q0a = qblk * 128 + wave * 16;
  const int q0b = q0a + 64;

  const u16* Kh = z ? K1 : K0;
  const u16* Vt = z ? V1 : V0;
  const int* kmb = (z ? km1 : km0) + b * T;
  u16* ctx = z ? ctx1 : ctx0;

  __shared__ u16 Plds[4][2][16 * 136];      // per-wave, per-chain P^T bounce
  u16* Pa = Plds[wave][0];
  u16* Pb = Plds[wave][1];

  const size_t qoffa = ((size_t)bh * L + q0a + qi) * 64;
  const size_t qoffb = ((size_t)bh * L + q0b + qi) * 64;
  const bf16x8 qa0 = *(const bf16x8*)(Q + qoffa + g * 8);
  const bf16x8 qa1 = *(const bf16x8*)(Q + qoffa + 32 + g * 8);
  const bf16x8 qb0 = *(const bf16x8*)(Q + qoffb + g * 8);
  const bf16x8 qb1 = *(const bf16x8*)(Q + qoffb + 32 + g * 8);

  const float qma = (float)qmask[b * L + q0a + qi];
  const float qmb = (float)qmask[b * L + q0b + qi];
  float tsa = 0.f, tsb = 0.f;
  f32x4 ofa[4] = {}, ofb[4] = {};

  for (int kb = 0; kb < T; kb += 128) {     // 4 iterations
    f32x4 sta[8], stb[8];
    __builtin_amdgcn_s_setprio(1);
#pragma unroll
    for (int s = 0; s < 8; ++s) {
      const size_t koff = ((size_t)bh * T + kb + s * 16 + qi) * 64;
      bf16x8 k0v = *(const bf16x8*)(Kh + koff + g * 8);
      bf16x8 k1v = *(const bf16x8*)(Kh + koff + 32 + g * 8);
      f32x4 za = {}; za = mfma16(k0v, qa0, za); sta[s] = mfma16(k1v, qa1, za);
      f32x4 zb = {}; zb = mfma16(k0v, qb0, zb); stb[s] = mfma16(k1v, qb1, zb);
    }
    __builtin_amdgcn_s_setprio(0);
#pragma unroll
    for (int s = 0; s < 8; ++s) {
      int4 km4 = *(const int4*)(kmb + kb + s * 16 + g * 4);
      const float m0 = km4.x ? 0.f : -1e30f;
      const float m1 = km4.y ? 0.f : -1e30f;
      const float m2 = km4.z ? 0.f : -1e30f;
      const float m3 = km4.w ? 0.f : -1e30f;
      float a0 = exp2f(fmaf(sta[s][0] + m0, qma, -20.f));
      float a1 = exp2f(fmaf(sta[s][1] + m1, qma, -20.f));
      float a2 = exp2f(fmaf(sta[s][2] + m2, qma, -20.f));
      float a3 = exp2f(fmaf(sta[s][3] + m3, qma, -20.f));
      tsa += (a0 + a1) + (a2 + a3);
      uint2 wa; wa.x = cvtpk(a0, a1); wa.y = cvtpk(a2, a3);
      *(uint2*)(Pa + qi * 136 + s * 16 + g * 4) = wa;
      float p0 = exp2f(fmaf(stb[s][0] + m0, qmb, -20.f));
      float p1 = exp2f(fmaf(stb[s][1] + m1, qmb, -20.f));
      float p2 = exp2f(fmaf(stb[s][2] + m2, qmb, -20.f));
      float p3 = exp2f(fmaf(stb[s][3] + m3, qmb, -20.f));
      tsb += (p0 + p1) + (p2 + p3);
      uint2 wb; wb.x = cvtpk(p0, p1); wb.y = cvtpk(p2, p3);
      *(uint2*)(Pb + qi * 136 + s * 16 + g * 4) = wb;
    }
    bf16x8 paf[4], pbf[4];
#pragma unroll
    for (int ks = 0; ks < 4; ++ks) {
      paf[ks] = *(const bf16x8*)(Pa + qi * 136 + ks * 32 + g * 8);
      pbf[ks] = *(const bf16x8*)(Pb + qi * 136 + ks * 32 + g * 8);
    }
    __builtin_amdgcn_s_setprio(1);
#pragma unroll
    for (int nf = 0; nf < 4; ++nf) {
      f32x4 oa = ofa[nf], ob = ofb[nf];
#pragma unroll
      for (int ks = 0; ks < 4; ++ks) {
        const size_t voff = ((size_t)bh * 64 + nf * 16 + qi) * (size_t)T + kb + ks * 32 + g * 8;
        bf16x8 vb = *(const bf16x8*)(Vt + voff);
        oa = mfma16(paf[ks], vb, oa);
        ob = mfma16(pbf[ks], vb, ob);
      }
      ofa[nf] = oa; ofb[nf] = ob;
    }
    __builtin_amdgcn_s_setprio(0);
  }
  tsa += __shfl_xor(tsa, 16); tsa += __shfl_xor(tsa, 32);
  tsb += __shfl_xor(tsb, 16); tsb += __shfl_xor(tsb, 32);
  const float lia = 1.f / tsa;
  const float lib = 1.f / tsb;
  float lja[4], ljb[4];
#pragma unroll
  for (int j = 0; j < 4; ++j) {
    lja[j] = __shfl(lia, g * 4 + j);
    ljb[j] = __shfl(lib, g * 4 + j);
  }
#pragma unroll
  for (int nf = 0; nf < 4; ++nf) {
    int col = h * 64 + nf * 16 + qi;
#pragma unroll
    for (int j = 0; j < 4; ++j) {
      int rowa = q0a + g * 4 + j;
      int rowb = q0b + g * 4 + j;
      ctx[((size_t)b * L + rowa) * 1024 + col] = f2bf(ofa[nf][j] * lja[j]);
      ctx[((size_t)b * L + rowb) * 1024 + col] = f2bf(ofb[nf][j] * ljb[j]);
    }
  }
}

// ---------------- driver ----------------
extern "C" void kernel_launch(void* const* d_in, const int* in_sizes, int n_in,
                              void* d_out, int out_size, void* d_ws, size_t ws_size,
                              hipStream_t stream)
{
  (void)in_sizes; (void)n_in; (void)out_size; (void)ws_size;
  const float* from = (const float*)d_in[0];
  const float* to_t = (const float*)d_in[1];
  const float* ln1g = (const float*)d_in[2];
  const float* ln1b = (const float*)d_in[3];
  const float* lntg = (const float*)d_in[4];
  const float* lntb = (const float*)d_in[5];
  const float* ln2g = (const float*)d_in[6];
  const float* ln2b = (const float*)d_in[7];
  const int* fmask = (const int*)d_in[38];
  const int* tmask = (const int*)d_in[39];

  char* ws = (char*)d_ws;
  const size_t MB = 1ull << 20;
  auto WT = [&](int i) { return (u16*)(ws + (size_t)i * 2 * MB); };   // slots 0..19 (40MB)
  // WT: 0 Wq^T 1 Wfk^T 2 Wfv^T 3 Wtk^T 4 Wtv^T 5 Ws^T 6 Wx^T 7 Wsg^T 8 Wxg^T
  //     9 Wg(plain) 10 W1^T 11 W2^T 12 Wd1^T 13 Wd2^T 14 Ws(plain) 15 Wx(plain)
  //     16 WcS^T=(Ws@Wsg)^T 17 WcX^T 18 WcG1^T=(Wg@W1)^T 19 WcG2^T
  float* bc_s   = (float*)(ws + 40 * MB);
  float* bc_x   = bc_s + 1024;
  float* bias1v = bc_s + 2048;
  float* bias2v = bc_s + 3072;
  u16*   xbf    = (u16*)(ws + 42 * MB);
  u16*   tbf    = (u16*)(ws + 50 * MB);
  u16*   qh     = (u16*)(ws + 58 * MB);
  u16*   fkh    = (u16*)(ws + 66 * MB);
  u16*   fvt    = (u16*)(ws + 74 * MB);
  u16*   tkh    = (u16*)(ws + 82 * MB);
  u16*   tvt    = (u16*)(ws + 90 * MB);
  u16*   xctx   = (u16*)(ws + 98 * MB);
  // temporally-disjoint reuse:
  u16*   sctx   = (u16*)(ws + 50 * MB);         // over tbf (dead after mega1)
  u16*   gated  = (u16*)(ws + 90 * MB);         // over tvt (dead after attn)
  u16*   abf    = (u16*)(ws + 98 * MB);         // over xctx (dead after quad)
  float* resid  = (float*)(ws + 58 * MB);       // 16MB over qh/fkh (dead after bilinear)
  u16*   lnr    = (u16*)(ws + 74 * MB);         // over fvt (dead)

  W16 wsrc;
  const int widx[14] = {8, 10, 12, 14, 16, 18, 20, 22, 24, 26, 28, 31, 34, 36};
  for (int i = 0; i < 14; ++i) wsrc.p[i] = (const float*)d_in[widx[i]];
  wsrc.p[14] = (const float*)d_in[18];   // Ws plain
  wsrc.p[15] = (const float*)d_in[20];   // Wx plain
  wconv<<<dim3(16, 16, 16), dim3(64, 4), 0, stream>>>(wsrc, (1u << 9) | (1u << 14) | (1u << 15), WT(0));

  {
    BiasJob j0{(const float*)d_in[19], (const float*)d_in[22], (const float*)d_in[23], nullptr, 1.f, bc_s};
    BiasJob j1{(const float*)d_in[21], (const float*)d_in[24], (const float*)d_in[25], nullptr, 1.f, bc_x};
    BiasJob j2{(const float*)d_in[27], (const float*)d_in[28], (const float*)d_in[29], (const float*)d_in[30], 2.f, bias1v};
    BiasJob j3{(const float*)d_in[27], (const float*)d_in[31], (const float*)d_in[32], (const float*)d_in[33], 2.f, bias2v};
    bias_comb<<<dim3(16, 4), 256, 0, stream>>>(j0, j1, j2, j3);
  }

  ln_bf16<<<8192, 256, 0, stream>>>(from, ln1g, ln1b, xbf, to_t, lntg, lntb, tbf, 4096);

  const int Kd = 1024;
  GOut z{};
  const int FAR = 0x7fffffff;

  // mega1 (BM=128, 512 thr, dbuf): QKV projections + weight combines (1536 blocks)
  {
    Segs S{};
    S.s[0] = {xbf, WT(0), {{qh,  (const float*)d_in[9],  nullptr, QSCALE, 1},
                           {fkh, (const float*)d_in[11], nullptr, 1.f,    1}}, 3, 16, 0};
    S.s[1] = {tbf, WT(3), {{tkh, (const float*)d_in[15], nullptr, 1.f, 1}, z}, 3, 8, 512};
    S.s[2] = {WT(2), xbf, {{fvt, (const float*)d_in[13], nullptr, 1.f, 5}, z}, 5, 32, 768};
    S.s[3] = {WT(4), tbf, {{tvt, (const float*)d_in[17], nullptr, 1.f, 5}, z}, 5, 32, 1024};
    S.s[4] = {WT(7),  WT(14), {{WT(16), nullptr, nullptr, 1.f, 0}, z}, 3, 8, 1280};
    S.s[5] = {WT(8),  WT(15), {{WT(17), nullptr, nullptr, 1.f, 0}, z}, 3, 8, 1344};
    S.s[6] = {WT(10), WT(9),  {{WT(18), nullptr, nullptr, 1.f, 0}, z}, 3, 8, 1408};
    S.s[7] = {WT(11), WT(9),  {{WT(19), nullptr, nullptr, 1.f, 0}, z}, 3, 8, 1472};
    S.total = 1536;
    gemm_multi<128, 512><<<1536, 512, 0, stream>>>(S, Kd);
  }

  attn_fused<<<1024, 256, 0, stream>>>(qh, fkh, fvt, tkh, tvt, fmask, fmask, tmask, sctx, xctx);

  // quad gate: gated = (sctx@WcS+bc_s)*(xctx@Wx+bx) + (xctx@WcX+bc_x)*(sctx@Ws+bs)
  gemm_quad_gate<<<512, 512, 0, stream>>>(sctx, xctx, WT(5), WT(6), WT(16), WT(17),
                                          (const float*)d_in[19], (const float*)d_in[21],
                                          bc_s, bc_x, gated);

  // bilinear K=2048: scores/values from {gated, xbf}, sigmoid-gate -> abf (512 blocks)
  gemm_bilinear<<<512, 512, 0, stream>>>(gated, xbf, WT(18), WT(10), WT(19), WT(11),
                                         bias1v, bias2v, fmask, abf);

  // G_G: abf @ Wd1 + bd1 + from -> resid (f32), BM=64, 512 blocks
  {
    Segs S{};
    S.s[0] = {abf, WT(12), {{resid, (const float*)d_in[35], from, 1.f, 3}, z}, 3, 8, 0};
    S.s[1].start = FAR; S.s[2].start = FAR; S.s[3].start = FAR;
    S.s[4].start = FAR; S.s[5].start = FAR; S.s[6].start = FAR; S.s[7].start = FAR;
    S.total = 512;
    gemm_multi<64, 256><<<512, 256, 0, stream>>>(S, Kd);
  }

  ln_bf16<<<4096, 256, 0, stream>>>(resid, ln2g, ln2b, lnr, resid, ln2g, ln2b, lnr, 4096);

  // G_H: lnr @ Wd2 + bd2 + resid -> out (f32), BM=64, 512 blocks
  {
    Segs S{};
    S.s[0] = {lnr, WT(13), {{d_out, (const float*)d_in[37], resid, 1.f, 3}, z}, 3, 8, 0};
    S.s[1].start = FAR; S.s[2].start = FAR; S.s[3].start = FAR;
    S.s[4].start = FAR; S.s[5].start = FAR; S.s[6].start = FAR; S.s[7].start = FAR;
    S.total = 512;
    gemm_multi<64, 256><<<512, 256, 0, stream>>>(S, Kd);
  }
}